// Round 3
// baseline (4514.982 us; speedup 1.0000x reference)
//
#include <hip/hip_runtime.h>
#include <math.h>

// LatentDecoder on MI355X. All f32. Rotations R eliminated (orthogonal, cancel
// around per-channel gates). Per-edge linear maps commuted to per-node + gather.
// R1: KNN window-seeded threshold scan (exact).
// R2: - alpha-edge logits fused into k_attn (p-edge + EW-alpha GEMMs deleted)
//     - ef@eW_e fused into k_edgeout (EW GEMM + buffer deleted; in-place safe)
//     - GEMM core: transposed As, 2x ds_read_b128 + 16 FMA per k-step
//     - ws re-layout (<128MB)

#define NN 8192
#define KK 30
#define NE (NN*KK)      // 245760
#define EPSF 1e-7f

// ---------------- workspace layout (bytes) ----------------
static const size_t O_SRC = 0;                  // int [NN*30]
static const size_t O_XS  = 1ull<<20;           // float[NN]*3
static const size_t O_YS  = O_XS + (size_t)NN*4;
static const size_t O_ZS  = O_XS + (size_t)NN*8;
static const size_t O_BBE = 2ull<<20;           // float[NN*4*26]   (3.4MB)
static const size_t O_RES = 6ull<<20;           // float[NN*4*64]   (8.4MB)
static const size_t O_P   = 15ull<<20;          // float[NN*4*32]   (4.2MB)
static const size_t O_EF  = 20ull<<20;          // float[NE*32]     (31.5MB, ends 51.5)
// layer-phase scratch (52MB+):
static const size_t O_NF  = 52ull<<20;          // float[NN*80]
static const size_t O_V1  = 55ull<<20;          // float[NN*3*64]
static const size_t O_O   = 62ull<<20;          // float[NN*4*64]
static const size_t O_T   = 71ull<<20;          // float[NN*4*64]
static const size_t O_EE  = 80ull<<20;          // float[NN*64]
// eb so3 phase (aliases layer scratch):
static const size_t O_M0E = 52ull<<20;          // float[NN*32]
static const size_t O_M1E = 54ull<<20;          // float[NN*3*32]
static const size_t O_HE  = 58ull<<20;          // float[61440*64]
static const size_t O_GE  = 74ull<<20;          // float[61440*64]  (ends 89.7)
// oa so3 phase (aliases layer scratch + res/p):
static const size_t O_M0O = 52ull<<20;          // float[NN*91]
static const size_t O_M1O = 56ull<<20;          // float[NN*3*91]   (ends 65.0)
static const size_t O_ATM = 6ull<<20;           // float[NN*4*91]   (res+p dead; ends 17.9)
static const size_t O_HO  = 66ull<<20;          // float[61440*64]  (ends 81.7)
static const size_t O_GO  = 82ull<<20;          // float[61440*182] (ends 126.7)
static const size_t O_BRP = 127ull<<20;         // repacked weights (<64KB)
static const size_t WS_NEEDED = O_BRP + (1ull<<16);

// ---------------- small device helpers ----------------
__device__ __forceinline__ float nn0(float v){ return (v != v) ? 0.f : v; }
__device__ __forceinline__ void norm3(float& x, float& y, float& z){
  float s = sqrtf(x*x + y*y + z*z + EPSF);
  x /= s; y /= s; z /= s;
}

// ---------------- prep: extract CA, build bbemb rows 1..3 + zeros ----------------
__global__ void k_prep(const float* __restrict__ bb, float* __restrict__ xs,
                       float* __restrict__ ys, float* __restrict__ zs,
                       float* __restrict__ bbe){
  int n = blockIdx.x*blockDim.x + threadIdx.x;
  if (n >= NN) return;
  const float* bn = bb + (size_t)n*12;
  float a0x=bn[0],a0y=bn[1],a0z=bn[2];
  float cax=bn[3],cay=bn[4],caz=bn[5];
  float a2x=bn[6],a2y=bn[7],a2z=bn[8];
  float a3x=bn[9],a3y=bn[10],a3z=bn[11];
  xs[n]=cax; ys[n]=cay; zs[n]=caz;
  float v[7][3];
  v[0][0]=a0x-cax; v[0][1]=a0y-cay; v[0][2]=a0z-caz;
  v[1][0]=0.f;     v[1][1]=0.f;     v[1][2]=0.f;
  v[2][0]=a2x-cax; v[2][1]=a2y-cay; v[2][2]=a2z-caz;
  v[3][0]=a3x-cax; v[3][1]=a3y-cay; v[3][2]=a3z-caz;
  if (n < NN-1){
    float fx=bb[(size_t)(n+1)*12+3]-cax, fy=bb[(size_t)(n+1)*12+4]-cay, fz=bb[(size_t)(n+1)*12+5]-caz;
    norm3(fx,fy,fz); v[4][0]=fx; v[4][1]=fy; v[4][2]=fz;
  } else { v[4][0]=v[4][1]=v[4][2]=0.f; }
  if (n > 0){
    float gx=bb[(size_t)(n-1)*12+3]-cax, gy=bb[(size_t)(n-1)*12+4]-cay, gz=bb[(size_t)(n-1)*12+5]-caz;
    norm3(gx,gy,gz); v[5][0]=gx; v[5][1]=gy; v[5][2]=gz;
  } else { v[5][0]=v[5][1]=v[5][2]=0.f; }
  {
    float bx=cax-a0x, by=cay-a0y, bz=caz-a0z;
    float cx=a2x-cax, cy=a2y-cay, cz=a2z-caz;
    float ax = by*cz - bz*cy, ay = bz*cx - bx*cz, az = bx*cy - by*cx;
    v[6][0] = -0.58273431f*ax + 0.56802827f*bx - 0.54067466f*cx;
    v[6][1] = -0.58273431f*ay + 0.56802827f*by - 0.54067466f*cy;
    v[6][2] = -0.58273431f*az + 0.56802827f*bz - 0.54067466f*cz;
  }
  float* be = bbe + (size_t)n*104;
  #pragma unroll
  for (int c=6;c<26;++c) be[c]=0.f;
  #pragma unroll
  for (int s=0;s<3;++s){
    float* br = be + 26*(1+s);
    #pragma unroll
    for (int c=0;c<26;++c) br[c] = (c<7) ? nn0(v[c][s]) : 0.f;
  }
}

// ---------------- dihedrals -> bbemb row0 cols 0..5 ----------------
__global__ void k_dihed(const float* __restrict__ bb, float* __restrict__ bbe){
  int t = blockIdx.x*blockDim.x + threadIdx.x;
  if (t >= 3*NN) return;
  float cD = 1.f, sD = 0.f;
  if (t >= 1 && t < 3*NN-2){
    int i = t-1;
    float p[4][3];
    #pragma unroll
    for (int m=0;m<4;++m){
      int a = i+m; int rn = a/3, ra = a - rn*3;
      const float* q = bb + (size_t)(rn*4 + ra)*3;
      p[m][0]=q[0]; p[m][1]=q[1]; p[m][2]=q[2];
    }
    float u2x=p[1][0]-p[0][0], u2y=p[1][1]-p[0][1], u2z=p[1][2]-p[0][2];
    float u1x=p[2][0]-p[1][0], u1y=p[2][1]-p[1][1], u1z=p[2][2]-p[1][2];
    float u0x=p[3][0]-p[2][0], u0y=p[3][1]-p[2][1], u0z=p[3][2]-p[2][2];
    norm3(u2x,u2y,u2z); norm3(u1x,u1y,u1z); norm3(u0x,u0y,u0z);
    float n2x=u2y*u1z-u2z*u1y, n2y=u2z*u1x-u2x*u1z, n2z=u2x*u1y-u2y*u1x;
    float n1x=u1y*u0z-u1z*u0y, n1y=u1z*u0x-u1x*u0z, n1z=u1x*u0y-u1y*u0x;
    norm3(n2x,n2y,n2z); norm3(n1x,n1y,n1z);
    float cosD = n2x*n1x + n2y*n1y + n2z*n1z;
    const float lo = (float)(-1.0 + 1e-7), hi = (float)(1.0 - 1e-7);
    cosD = fminf(fmaxf(cosD, lo), hi);
    float sg = u2x*n1x + u2y*n1y + u2z*n1z;
    float sgn = (sg > 0.f) ? 1.f : ((sg < 0.f) ? -1.f : 0.f);
    float D = sgn * acosf(cosD);
    cD = cosf(D); sD = sinf(D);
  }
  int n = t/3, col = t - n*3;
  bbe[(size_t)n*104 + col] = cD;
  bbe[(size_t)n*104 + 3 + col] = sD;
}

// ---------------- KNN: wave per query, window-seeded exact top-30 ----------------
__global__ __launch_bounds__(256) void k_knn(const float* __restrict__ xs,
        const float* __restrict__ ys, const float* __restrict__ zs, int* __restrict__ src){
  __shared__ float sd[4][32];
  __shared__ int   si[4][32];
  int w = threadIdx.x >> 6, lane = threadIdx.x & 63;
  int n = blockIdx.x*4 + w;
  float qx = xs[n], qy = ys[n], qz = zs[n];
  if (lane >= 30 && lane < 32){ sd[w][lane] = INFINITY; si[w][lane] = 0; }

  int w0 = n - 32; if (w0 < 0) w0 = 0; if (w0 > NN-64) w0 = NN-64;
  int idx = w0 + lane;
  {
    float dx = qx - xs[idx], dy = qy - ys[idx], dz = qz - zs[idx];
    float d2 = dx*dx + dy*dy + dz*dz;
    if (idx == n) d2 = INFINITY;
    #pragma unroll
    for (int k = 2; k <= 64; k <<= 1){
      #pragma unroll
      for (int jj = k>>1; jj >= 1; jj >>= 1){
        float od = __shfl_xor(d2, jj);
        int   oi = __shfl_xor(idx, jj);
        bool up      = ((lane & k) == 0);
        bool lower   = ((lane & jj) == 0);
        bool takeMin = (up == lower);
        bool mless   = (d2 < od) || (d2 == od && idx < oi);
        if (mless != takeMin){ d2 = od; idx = oi; }
      }
    }
    if (lane < 30){ sd[w][lane] = d2; si[w][lane] = idx; }
  }
  float thr = sd[w][29];

  for (int s = 0; s < NN/64; ++s){
    int j = s*64 + lane;
    float dx = __fsub_rn(qx, xs[j]);
    float dy = __fsub_rn(qy, ys[j]);
    float dz = __fsub_rn(qz, zs[j]);
    float d2 = __fadd_rn(__fadd_rn(__fmul_rn(dx,dx),__fmul_rn(dy,dy)),__fmul_rn(dz,dz));
    if (j == n) d2 = INFINITY;
    if (j >= w0 && j < w0+64) d2 = INFINITY;
    unsigned long long bal = __ballot(d2 < thr);
    if (bal){
      while (bal){
        int b = __ffsll((unsigned long long)bal) - 1;
        bal &= bal - 1ull;
        float vd = __shfl(d2, b);
        int vj = s*64 + b;
        float dl = 0.f; int il = 0; bool keep = true;
        if (lane < 30){ dl = sd[w][lane]; il = si[w][lane]; keep = (dl <= vd); }
        unsigned long long km = __ballot(lane < 30 && keep);
        int pos = __popcll(km);
        if (lane < 30 && !keep){ sd[w][lane+1] = dl; si[w][lane+1] = il; }
        if (lane == pos){ sd[w][lane] = vd; si[w][lane] = vj; }
      }
      thr = sd[w][29];
    }
  }
  if (lane < 30) src[(size_t)n*KK + lane] = si[w][lane];
}

// ---------------- edge features: rbf(16) + pos_emb(16) ----------------
__global__ void k_edgefeat(const int* __restrict__ src, const float* __restrict__ xs,
        const float* __restrict__ ys, const float* __restrict__ zs, float* __restrict__ ef){
  int e = blockIdx.x*blockDim.x + threadIdx.x;
  if (e >= NE) return;
  int n = e / KK;
  int j = src[e];
  float vx = xs[j]-xs[n], vy = ys[j]-ys[n], vz = zs[j]-zs[n];
  float dist = sqrtf(vx*vx + vy*vy + vz*vz + EPSF);
  float* o = ef + (size_t)e*32;
  #pragma unroll
  for (int m=0;m<16;++m){
    float mu = (float)m * (20.f/15.f);
    float q = (dist - mu) / 1.25f;
    o[m] = expf(-q*q);
  }
  float d = (float)(j - n);
  const float Cf = -0.5756462732485115f;   // -ln(1e4)/16
  #pragma unroll
  for (int fi=0; fi<8; ++fi){
    float fr = expf((float)(2*fi) * Cf);
    float ang = d * fr;
    o[16+fi] = cosf(ang);
    o[24+fi] = sinf(ang);
  }
}

// ---------------- generic f32 GEMM: C[M,Nc] = act(A@B + bias) (+C if beta) ----------------
// As transposed [k][row] with pad-4 stride (16B aligned): inner loop = 2x b128 + 16 FMA.
// A row r -> A + (r/arpg)*agst + (r%arpg)*arst + aoff  (arpg in {1,3})
template<int K, int ACT>
__global__ __launch_bounds__(256) void k_gemm(const float* __restrict__ A,
        const float* __restrict__ B, const float* __restrict__ bias, float* __restrict__ C,
        int M, int Nc, int arpg, int agst, int arst, int aoff, int beta){
  __shared__ alignas(16) float As[K*68];   // [kk][row], stride 68
  __shared__ alignas(16) float Bs[K*64];   // [kk][col]
  int tid = threadIdx.x, tm = blockIdx.x, tn = blockIdx.y;
  for (int i = tid; i < K*64; i += 256){
    int kk = i >> 6, cl = i & 63;
    int c = tn*64 + cl;
    Bs[i] = (c < Nc) ? B[kk*Nc + c] : 0.f;
  }
  for (int i = tid; i < 64*K; i += 256){
    int rl = i / K, kk = i - rl*K;
    int r = tm*64 + rl;
    float v = 0.f;
    if (r < M){
      const float* ap;
      if (arpg == 1) ap = A + (size_t)r*agst + aoff;
      else { int g = r/3; int wr = r - g*3; ap = A + (size_t)g*agst + wr*arst + aoff; }
      v = ap[kk];
    }
    As[kk*68 + rl] = v;
  }
  __syncthreads();
  int tx = tid & 15, ty = tid >> 4;
  float acc[4][4] = {};
  #pragma unroll
  for (int kk = 0; kk < K; ++kk){
    float4 a4 = *reinterpret_cast<const float4*>(&As[kk*68 + ty*4]);
    float4 b4 = *reinterpret_cast<const float4*>(&Bs[kk*64 + tx*4]);
    acc[0][0] += a4.x*b4.x; acc[0][1] += a4.x*b4.y; acc[0][2] += a4.x*b4.z; acc[0][3] += a4.x*b4.w;
    acc[1][0] += a4.y*b4.x; acc[1][1] += a4.y*b4.y; acc[1][2] += a4.y*b4.z; acc[1][3] += a4.y*b4.w;
    acc[2][0] += a4.z*b4.x; acc[2][1] += a4.z*b4.y; acc[2][2] += a4.z*b4.z; acc[2][3] += a4.z*b4.w;
    acc[3][0] += a4.w*b4.x; acc[3][1] += a4.w*b4.y; acc[3][2] += a4.w*b4.z; acc[3][3] += a4.w*b4.w;
  }
  #pragma unroll
  for (int rr = 0; rr < 4; ++rr){
    int r = tm*64 + ty*4 + rr;
    if (r >= M) continue;
    #pragma unroll
    for (int cc = 0; cc < 4; ++cc){
      int c = tn*64 + tx*4 + cc;
      if (c >= Nc) continue;
      float v = acc[rr][cc];
      if (bias) v += bias[c];
      if (ACT == 1) v = v / (1.f + expf(-v));   // silu
      size_t ci = (size_t)r*Nc + c;
      if (beta) v += C[ci];
      C[ci] = v;
    }
  }
}

// ---------------- fused attention: inline alpha-edge logits + softmax + gather ----------------
// NF: [A1(8)|A2(8)|V0(64)] per node; V1: (N,3,64); WaE: [32][8] edge part of Walpha
__global__ __launch_bounds__(256) void k_attn(const int* __restrict__ src,
        const float* __restrict__ NF, const float* __restrict__ V1,
        const float* __restrict__ ef, const float* __restrict__ WaE, float* __restrict__ o){
  int w = threadIdx.x >> 6, lane = threadIdx.x & 63;
  int n = blockIdx.x*4 + w;
  int h = lane >> 3, q = lane & 7;
  // per-lane alpha-edge weights: rows q*4..q*4+3, col h
  float w0 = WaE[(q*4+0)*8 + h];
  float w1 = WaE[(q*4+1)*8 + h];
  float w2 = WaE[(q*4+2)*8 + h];
  float w3 = WaE[(q*4+3)*8 + h];
  const int* sk = src + (size_t)n*KK;
  int myj = (lane < KK) ? sk[lane] : 0;
  float a2 = NF[(size_t)n*80 + 8 + h];
  float m = -INFINITY, s = 0.f, o0=0.f, o1=0.f, o2=0.f, o3=0.f;
  for (int k = 0; k < KK; ++k){
    int j = __shfl(myj, k);
    float4 e4 = *reinterpret_cast<const float4*>(ef + ((size_t)n*KK + k)*32 + q*4);
    float val = e4.x*w0 + e4.y*w1 + e4.z*w2 + e4.w*w3;
    val += __shfl_xor(val, 1);
    val += __shfl_xor(val, 2);
    val += __shfl_xor(val, 4);
    float l = val + NF[(size_t)j*80 + h] + a2;
    l = (l >= 0.f) ? l : 0.2f*l;
    float mn = fmaxf(m, l);
    float f = expf(m - mn);
    float pp = expf(l - mn);
    s = s*f + pp;
    const float* v1p = V1 + (size_t)j*192;
    o0 = o0*f + pp*NF[(size_t)j*80 + 16 + lane];
    o1 = o1*f + pp*v1p[lane];
    o2 = o2*f + pp*v1p[64+lane];
    o3 = o3*f + pp*v1p[128+lane];
    m = mn;
  }
  float inv = 1.f/s;
  float* op = o + (size_t)n*256;
  op[lane] = o0*inv; op[64+lane] = o1*inv; op[128+lane] = o2*inv; op[192+lane] = o3*inv;
}

// ---------------- so3 gather-aggregate ----------------
template<int C>
__global__ void k_so3agg(const int* __restrict__ src, const float* __restrict__ G,
        const float* __restrict__ M0, const float* __restrict__ M1, float* __restrict__ out,
        int n0, int nodes, int nstr, int sstr){
  int t = blockIdx.x*blockDim.x + threadIdx.x;
  if (t >= nodes*C) return;
  int nl = t / C, c = t - nl*C;
  int n = n0 + nl;
  const int* sk = src + (size_t)n*KK;
  const float* gb = G + (size_t)nl*KK*2*C;
  float a0=0.f,a1=0.f,a2=0.f,a3=0.f;
  for (int k=0;k<KK;++k){
    int j = sk[k];
    float g0 = gb[k*2*C + c], g1 = gb[k*2*C + C + c];
    a0 += g0 * M0[(size_t)j*C + c];
    const float* m1p = M1 + (size_t)j*3*C;
    a1 += g1*m1p[c]; a2 += g1*m1p[C+c]; a3 += g1*m1p[2*C+c];
  }
  const float SQ = 5.477225575051661f;  // sqrt(30)
  float* ob = out + (size_t)n*nstr + c;
  ob[0] = a0/SQ; ob[sstr] = a1/SQ; ob[2*sstr] = a2/SQ; ob[3*sstr] = a3/SQ;
}

// ---------------- latent copy into res cols 32..63 ----------------
__global__ void k_lat(const float* __restrict__ latent, float* __restrict__ res){
  int t = blockIdx.x*blockDim.x + threadIdx.x;
  if (t >= NN*128) return;
  int n = t >> 7, rc = t & 127, s = rc >> 5, c = rc & 31;
  res[(size_t)n*256 + s*64 + 32 + c] = latent[t];
}

// ---------------- swiglu-style FFN gate ----------------
template<int C>
__global__ void k_swiglu(const float* __restrict__ T, float* __restrict__ U){
  int t = blockIdx.x*blockDim.x + threadIdx.x;
  if (t >= NN*C) return;
  int n = t / C, c = t - n*C;
  const float* tp = T + (size_t)n*4*C + c;
  float t0 = tp[0];
  float g = 1.f/(1.f + expf(-t0));
  float* up = U + (size_t)n*4*C + c;
  up[0]   = t0*g;
  up[C]   = tp[C]*g;
  up[2*C] = tp[2*C]*g;
  up[3*C] = tp[3*C]*g;
}

// ---------------- edge feature update (fused ef@eW_e matvec, in-place) ----------------
// Blocks own disjoint 8-edge groups; all reads of ef happen in the staged LDS copy
// before __syncthreads, writes after -> in-place safe.
__global__ __launch_bounds__(256) void k_edgeout(const int* __restrict__ src,
        const float* __restrict__ eWe, const float* __restrict__ EE,
        const float* __restrict__ ebv, float* __restrict__ ef){
  __shared__ float ws[32*32];
  __shared__ float es[8*32];
  int tid = threadIdx.x;
  size_t e0 = (size_t)blockIdx.x*8;
  for (int i = tid; i < 1024; i += 256) ws[i] = eWe[i];   // [kk][c] row-major
  es[tid] = ef[e0*32 + tid];
  __syncthreads();
  int le = tid >> 5, c = tid & 31;
  size_t e = e0 + le;
  int n = (int)(e / KK);
  int j = src[e];
  float acc = ebv[c] + EE[(size_t)j*64 + c] + EE[(size_t)n*64 + 32 + c];
  const float* er = es + le*32;
  #pragma unroll
  for (int kk = 0; kk < 32; ++kk) acc += er[kk]*ws[kk*32 + c];
  ef[e*32 + c] = tanhf(acc);
}

// ---------------- per-layer weight repack ----------------
// Bnode(64,80)=[Wa_src|Wa_dst|Wv0], Bee(64,64)=[eW_src|eW_dst]
__global__ void k_repack(const float* __restrict__ Wa, const float* __restrict__ Wv0,
        const float* __restrict__ eW, float* __restrict__ Bnode, float* __restrict__ Bee){
  int t = blockIdx.x*blockDim.x + threadIdx.x;
  if (t < 5120){
    int k = t/80, c = t - k*80;
    Bnode[t] = (c<8) ? Wa[k*8+c] : ((c<16) ? Wa[(64+k)*8 + (c-8)] : Wv0[k*64 + (c-16)]);
  } else if (t < 9216){
    int i = t - 5120; int k = i >> 6, c = i & 63;
    Bee[i] = (c<32) ? eW[k*32 + c] : eW[(64+k)*32 + (c-32)];
  }
}

// ---------------- head: LN + seq logits + transpose decoded ----------------
__global__ __launch_bounds__(128) void k_head(const float* __restrict__ atoms,
        const float* __restrict__ ln_g, const float* __restrict__ ln_b,
        const float* __restrict__ W_seq, const float* __restrict__ b_seq, float* __restrict__ out){
  __shared__ float red[128];
  __shared__ float nrm[91];
  __shared__ float lg[20];
  int n = blockIdx.x, t = threadIdx.x;
  const float* inv = atoms + (size_t)n*364;
  float x = (t < 91) ? inv[t] : 0.f;
  red[t] = x; __syncthreads();
  for (int off=64; off>=1; off>>=1){ if (t<off) red[t]+=red[t+off]; __syncthreads(); }
  float mu = red[0] / 91.f;
  __syncthreads();
  float d = x - mu;
  red[t] = (t<91) ? d*d : 0.f; __syncthreads();
  for (int off=64; off>=1; off>>=1){ if (t<off) red[t]+=red[t+off]; __syncthreads(); }
  float var = red[0] / 91.f;
  __syncthreads();
  if (t < 91) nrm[t] = (x - mu)/sqrtf(var + 1e-5f) * ln_g[t] + ln_b[t];
  __syncthreads();
  if (t < 20){
    float acc = b_seq[t];
    for (int c=0;c<91;++c) acc += nrm[c]*W_seq[c*20+t];
    lg[t] = acc;
  }
  __syncthreads();
  if (t == 0){
    float mx = lg[0];
    for (int i=1;i<20;++i) mx = fmaxf(mx, lg[i]);
    float s = 0.f;
    for (int i=0;i<20;++i) s += expf(lg[i]-mx);
    red[0] = mx + logf(s);
  }
  __syncthreads();
  float lse = red[0];
  if (t < 20) out[(size_t)NN*273 + (size_t)n*20 + t] = lg[t] - lse;
  for (int idx = t; idx < 273; idx += 128){
    int c = idx/3, i = idx - c*3;
    out[(size_t)n*273 + idx] = atoms[(size_t)n*364 + (1+i)*91 + c];
  }
}

// ---------------- host dispatch ----------------
static void gemm(hipStream_t st, int K, int act, const float* A, const float* B,
                 const float* bias, float* C, int M, int Nc,
                 int arpg, int agst, int arst, int aoff, int beta){
  dim3 g((M+63)/64, (Nc+63)/64), b(256);
  if (K == 26){
    k_gemm<26,0><<<g,b,0,st>>>(A,B,bias,C,M,Nc,arpg,agst,arst,aoff,beta);
  } else if (K == 32){
    if (act) k_gemm<32,1><<<g,b,0,st>>>(A,B,bias,C,M,Nc,arpg,agst,arst,aoff,beta);
    else     k_gemm<32,0><<<g,b,0,st>>>(A,B,bias,C,M,Nc,arpg,agst,arst,aoff,beta);
  } else {
    if (act) k_gemm<64,1><<<g,b,0,st>>>(A,B,bias,C,M,Nc,arpg,agst,arst,aoff,beta);
    else     k_gemm<64,0><<<g,b,0,st>>>(A,B,bias,C,M,Nc,arpg,agst,arst,aoff,beta);
  }
}

extern "C" void kernel_launch(void* const* d_in, const int* in_sizes, int n_in,
                              void* d_out, int out_size, void* d_ws, size_t ws_size,
                              hipStream_t stream){
  (void)in_sizes; (void)n_in; (void)out_size;
  if (ws_size < WS_NEEDED) return;

  const float* bb      = (const float*)d_in[0];
  const float* latent  = (const float*)d_in[2];
  const float* eb_Wrad = (const float*)d_in[3];
  const float* eb_brad = (const float*)d_in[4];
  const float* eb_Wgate= (const float*)d_in[5];
  const float* eb_W0   = (const float*)d_in[6];
  const float* eb_W1   = (const float*)d_in[7];
  const float* t_Walpha= (const float*)d_in[8];
  const float* t_Wv0   = (const float*)d_in[9];
  const float* t_Wv1   = (const float*)d_in[10];
  const float* t_Wo    = (const float*)d_in[11];
  const float* t_Wf1   = (const float*)d_in[12];
  const float* t_Wf2   = (const float*)d_in[13];
  const float* e_W     = (const float*)d_in[14];
  const float* e_b     = (const float*)d_in[15];
  const float* p_Walpha= (const float*)d_in[16];
  const float* p_Wv0   = (const float*)d_in[17];
  const float* p_Wv1   = (const float*)d_in[18];
  const float* p_Wo    = (const float*)d_in[19];
  const float* p_Wf1   = (const float*)d_in[20];
  const float* p_Wf2   = (const float*)d_in[21];
  const float* oa_Wrad = (const float*)d_in[22];
  const float* oa_brad = (const float*)d_in[23];
  const float* oa_Wgate= (const float*)d_in[24];
  const float* oa_W0   = (const float*)d_in[25];
  const float* oa_W1   = (const float*)d_in[26];
  const float* ln_g    = (const float*)d_in[27];
  const float* ln_b    = (const float*)d_in[28];
  const float* W_seq   = (const float*)d_in[29];
  const float* b_seq   = (const float*)d_in[30];

  char* w = (char*)d_ws;
  int*   src = (int*)  (w + O_SRC);
  float* xs  = (float*)(w + O_XS);
  float* ys  = (float*)(w + O_YS);
  float* zs  = (float*)(w + O_ZS);
  float* bbe = (float*)(w + O_BBE);
  float* res = (float*)(w + O_RES);
  float* p   = (float*)(w + O_P);
  float* ef  = (float*)(w + O_EF);
  float* NF  = (float*)(w + O_NF);
  float* V1  = (float*)(w + O_V1);
  float* o   = (float*)(w + O_O);
  float* T   = (float*)(w + O_T);
  float* EE  = (float*)(w + O_EE);
  float* M0e = (float*)(w + O_M0E);
  float* M1e = (float*)(w + O_M1E);
  float* He  = (float*)(w + O_HE);
  float* Ge  = (float*)(w + O_GE);
  float* M0o = (float*)(w + O_M0O);
  float* M1o = (float*)(w + O_M1O);
  float* atm = (float*)(w + O_ATM);
  float* Ho  = (float*)(w + O_HO);
  float* Go  = (float*)(w + O_GO);
  float* Bnode = (float*)(w + O_BRP);
  float* Bee   = (float*)(w + O_BRP + 32768);

  // ---- geometry ----
  k_prep <<<(NN+255)/256, 256, 0, stream>>>(bb, xs, ys, zs, bbe);
  k_dihed<<<(3*NN+255)/256, 256, 0, stream>>>(bb, bbe);
  k_knn  <<<NN/4, 256, 0, stream>>>(xs, ys, zs, src);
  k_edgefeat<<<(NE+255)/256, 256, 0, stream>>>(src, xs, ys, zs, ef);

  // ---- eb so3_conv -> res[:,:,0:32] ----
  gemm(stream, 26,0, bbe, eb_W0, nullptr, M0e, NN,   32, 1,104, 0, 0, 0);
  gemm(stream, 26,0, bbe, eb_W1, nullptr, M1e, 3*NN, 32, 3,104,26,26, 0);
  for (int cz=0; cz<4; ++cz){
    int n0 = cz*2048, me = 2048*KK;
    gemm(stream, 32,1, ef + (size_t)n0*KK*32, eb_Wrad, eb_brad, He, me, 64, 1,32,0,0, 0);
    gemm(stream, 64,0, He, eb_Wgate, nullptr, Ge, me, 64, 1,64,0,0, 0);
    k_so3agg<32><<<(2048*32+255)/256, 256, 0, stream>>>(src, Ge, M0e, M1e, res, n0, 2048, 256, 64);
  }
  k_lat<<<(NN*128+255)/256, 256, 0, stream>>>(latent, res);

  // ---- transformer layers ----
  for (int L=0; L<4; ++L){
    const float* Wa  = t_Walpha + (size_t)L*160*8;
    const float* Wv0 = t_Wv0 + (size_t)L*64*64;
    const float* Wv1 = t_Wv1 + (size_t)L*64*64;
    const float* Wo  = t_Wo  + (size_t)L*64*64;
    const float* Wf1 = t_Wf1 + (size_t)L*64*64;
    const float* Wf2 = t_Wf2 + (size_t)L*64*64;
    const float* eWl = e_W   + (size_t)L*160*32;
    const float* ebl = e_b   + (size_t)L*32;
    k_repack<<<36, 256, 0, stream>>>(Wa, Wv0, eWl, Bnode, Bee);
    gemm(stream, 64,0, res, Bnode, nullptr, NF, NN,   80, 1,256, 0, 0, 0);
    gemm(stream, 64,0, res, Wv1,   nullptr, V1, 3*NN, 64, 3,256,64,64, 0);
    k_attn<<<NN/4, 256, 0, stream>>>(src, NF, V1, ef, Wa + 128*8, o);
    gemm(stream, 64,0, o,   Wo,  nullptr, res, 4*NN, 64, 1,64,0,0, 1);
    gemm(stream, 64,0, res, Wf1, nullptr, T,   4*NN, 64, 1,64,0,0, 0);
    k_swiglu<64><<<(NN*64+255)/256, 256, 0, stream>>>(T, o);
    gemm(stream, 64,0, o,   Wf2, nullptr, res, 4*NN, 64, 1,64,0,0, 1);
    gemm(stream, 64,0, res, Bee, nullptr, EE,  NN,   64, 1,256,0,0, 0);
    k_edgeout<<<NE/8, 256, 0, stream>>>(src, eWl + 128*32, EE, ebl, ef);
  }

  // ---- p = attn(res) + ffn ----
  k_repack<<<36, 256, 0, stream>>>(p_Walpha, p_Wv0, e_W, Bnode, Bee);  // Bee unused here
  gemm(stream, 64,0, res, Bnode, nullptr, NF, NN,   80, 1,256, 0, 0, 0);
  gemm(stream, 64,0, res, p_Wv1, nullptr, V1, 3*NN, 64, 3,256,64,64, 0);
  k_attn<<<NN/4, 256, 0, stream>>>(src, NF, V1, ef, p_Walpha + 128*8, o);
  gemm(stream, 64,0, o, p_Wo,  nullptr, p, 4*NN, 32, 1,64,0,0, 0);
  gemm(stream, 32,0, p, p_Wf1, nullptr, T, 4*NN, 32, 1,32,0,0, 0);
  k_swiglu<32><<<(NN*32+255)/256, 256, 0, stream>>>(T, o);
  gemm(stream, 32,0, o, p_Wf2, nullptr, p, 4*NN, 32, 1,32,0,0, 1);

  // ---- oa so3_conv -> atoms ----
  gemm(stream, 32,0, p, oa_W0, nullptr, M0o, NN,   91, 1,128, 0, 0, 0);
  gemm(stream, 32,0, p, oa_W1, nullptr, M1o, 3*NN, 91, 3,128,32,32, 0);
  for (int cz=0; cz<4; ++cz){
    int n0 = cz*2048, me = 2048*KK;
    gemm(stream, 32,1, ef + (size_t)n0*KK*32, oa_Wrad, oa_brad, Ho, me, 64, 1,32,0,0, 0);
    gemm(stream, 64,0, Ho, oa_Wgate, nullptr, Go, me, 182, 1,64,0,0, 0);
    k_so3agg<91><<<(2048*91+255)/256, 256, 0, stream>>>(src, Go, M0o, M1o, atm, n0, 2048, 364, 91);
  }

  // ---- head ----
  k_head<<<NN, 128, 0, stream>>>(atm, ln_g, ln_b, W_seq, b_seq, (float*)d_out);
}

// Round 4
// 1398.368 us; speedup vs baseline: 3.2288x; 3.2288x over previous
//
#include <hip/hip_runtime.h>
#include <math.h>

// LatentDecoder on MI355X. All f32. Rotations R eliminated (orthogonal, cancel
// around per-channel gates). Per-edge linear maps commuted to per-node + gather.
// R1: KNN window-seeded threshold scan (exact).
// R2: alpha-edge logits fused into k_attn; ef@eW_e fused into k_edgeout.
// R3 (regression, reverted): transposed-As GEMM core -> VGPR 256 + LDS conflicts.
// R4: - GEMM core reverted to R2 form (row-major As, 0 conflicts, VGPR 136)
//     - gate MLP + so3 aggregate fused into one per-node kernel (k_so3fused):
//       deletes H/G HBM round-trips (~600MB) and ~24 dispatches
//     - swiglu fused into Wf1 GEMM epilogue (ACT=2)
//     - k_repack deleted (BSEL column mapping in GEMM B-staging)

#define NN 8192
#define KK 30
#define NE (NN*KK)      // 245760
#define EPSF 1e-7f

// ---------------- workspace layout (bytes) ----------------
static const size_t O_SRC = 0;                  // int [NN*30]
static const size_t O_XS  = 1ull<<20;
static const size_t O_YS  = O_XS + (size_t)NN*4;
static const size_t O_ZS  = O_XS + (size_t)NN*8;
static const size_t O_BBE = 2ull<<20;           // float[NN*4*26]  (ends 5.3MB)
static const size_t O_RES = 6ull<<20;           // float[NN*4*64]  (ends 14MB)
static const size_t O_P   = 15ull<<20;          // float[NN*4*32]  (ends 19MB)
static const size_t O_EF  = 20ull<<20;          // float[NE*32]    (ends 50MB)
// layer-phase scratch:
static const size_t O_NF  = 52ull<<20;          // float[NN*80]
static const size_t O_V1  = 55ull<<20;          // float[NN*3*64]
static const size_t O_O   = 62ull<<20;          // float[NN*4*64]  (ends 70MB)
static const size_t O_EE  = 71ull<<20;          // float[NN*64]    (ends 73MB)
// eb so3 phase (aliases layer scratch):
static const size_t O_M0E = 52ull<<20;          // float[NN*32]
static const size_t O_M1E = 54ull<<20;          // float[NN*3*32]
// oa so3 phase (aliases layer scratch + res/p, all dead by then):
static const size_t O_M0O = 52ull<<20;          // float[NN*91]
static const size_t O_M1O = 56ull<<20;          // float[NN*3*91]  (ends 64.5MB)
static const size_t O_ATM = 6ull<<20;           // float[NN*4*91]  (ends 17.4MB)
static const size_t WS_NEEDED = 80ull<<20;

// ---------------- small device helpers ----------------
__device__ __forceinline__ float nn0(float v){ return (v != v) ? 0.f : v; }
__device__ __forceinline__ void norm3(float& x, float& y, float& z){
  float s = sqrtf(x*x + y*y + z*z + EPSF);
  x /= s; y /= s; z /= s;
}

// ---------------- prep: extract CA, build bbemb rows 1..3 + zeros ----------------
__global__ void k_prep(const float* __restrict__ bb, float* __restrict__ xs,
                       float* __restrict__ ys, float* __restrict__ zs,
                       float* __restrict__ bbe){
  int n = blockIdx.x*blockDim.x + threadIdx.x;
  if (n >= NN) return;
  const float* bn = bb + (size_t)n*12;
  float a0x=bn[0],a0y=bn[1],a0z=bn[2];
  float cax=bn[3],cay=bn[4],caz=bn[5];
  float a2x=bn[6],a2y=bn[7],a2z=bn[8];
  float a3x=bn[9],a3y=bn[10],a3z=bn[11];
  xs[n]=cax; ys[n]=cay; zs[n]=caz;
  float v[7][3];
  v[0][0]=a0x-cax; v[0][1]=a0y-cay; v[0][2]=a0z-caz;
  v[1][0]=0.f;     v[1][1]=0.f;     v[1][2]=0.f;
  v[2][0]=a2x-cax; v[2][1]=a2y-cay; v[2][2]=a2z-caz;
  v[3][0]=a3x-cax; v[3][1]=a3y-cay; v[3][2]=a3z-caz;
  if (n < NN-1){
    float fx=bb[(size_t)(n+1)*12+3]-cax, fy=bb[(size_t)(n+1)*12+4]-cay, fz=bb[(size_t)(n+1)*12+5]-caz;
    norm3(fx,fy,fz); v[4][0]=fx; v[4][1]=fy; v[4][2]=fz;
  } else { v[4][0]=v[4][1]=v[4][2]=0.f; }
  if (n > 0){
    float gx=bb[(size_t)(n-1)*12+3]-cax, gy=bb[(size_t)(n-1)*12+4]-cay, gz=bb[(size_t)(n-1)*12+5]-caz;
    norm3(gx,gy,gz); v[5][0]=gx; v[5][1]=gy; v[5][2]=gz;
  } else { v[5][0]=v[5][1]=v[5][2]=0.f; }
  {
    float bx=cax-a0x, by=cay-a0y, bz=caz-a0z;
    float cx=a2x-cax, cy=a2y-cay, cz=a2z-caz;
    float ax = by*cz - bz*cy, ay = bz*cx - bx*cz, az = bx*cy - by*cx;
    v[6][0] = -0.58273431f*ax + 0.56802827f*bx - 0.54067466f*cx;
    v[6][1] = -0.58273431f*ay + 0.56802827f*by - 0.54067466f*cy;
    v[6][2] = -0.58273431f*az + 0.56802827f*bz - 0.54067466f*cz;
  }
  float* be = bbe + (size_t)n*104;
  #pragma unroll
  for (int c=6;c<26;++c) be[c]=0.f;
  #pragma unroll
  for (int s=0;s<3;++s){
    float* br = be + 26*(1+s);
    #pragma unroll
    for (int c=0;c<26;++c) br[c] = (c<7) ? nn0(v[c][s]) : 0.f;
  }
}

// ---------------- dihedrals -> bbemb row0 cols 0..5 ----------------
__global__ void k_dihed(const float* __restrict__ bb, float* __restrict__ bbe){
  int t = blockIdx.x*blockDim.x + threadIdx.x;
  if (t >= 3*NN) return;
  float cD = 1.f, sD = 0.f;
  if (t >= 1 && t < 3*NN-2){
    int i = t-1;
    float p[4][3];
    #pragma unroll
    for (int m=0;m<4;++m){
      int a = i+m; int rn = a/3, ra = a - rn*3;
      const float* q = bb + (size_t)(rn*4 + ra)*3;
      p[m][0]=q[0]; p[m][1]=q[1]; p[m][2]=q[2];
    }
    float u2x=p[1][0]-p[0][0], u2y=p[1][1]-p[0][1], u2z=p[1][2]-p[0][2];
    float u1x=p[2][0]-p[1][0], u1y=p[2][1]-p[1][1], u1z=p[2][2]-p[1][2];
    float u0x=p[3][0]-p[2][0], u0y=p[3][1]-p[2][1], u0z=p[3][2]-p[2][2];
    norm3(u2x,u2y,u2z); norm3(u1x,u1y,u1z); norm3(u0x,u0y,u0z);
    float n2x=u2y*u1z-u2z*u1y, n2y=u2z*u1x-u2x*u1z, n2z=u2x*u1y-u2y*u1x;
    float n1x=u1y*u0z-u1z*u0y, n1y=u1z*u0x-u1x*u0z, n1z=u1x*u0y-u1y*u0x;
    norm3(n2x,n2y,n2z); norm3(n1x,n1y,n1z);
    float cosD = n2x*n1x + n2y*n1y + n2z*n1z;
    const float lo = (float)(-1.0 + 1e-7), hi = (float)(1.0 - 1e-7);
    cosD = fminf(fmaxf(cosD, lo), hi);
    float sg = u2x*n1x + u2y*n1y + u2z*n1z;
    float sgn = (sg > 0.f) ? 1.f : ((sg < 0.f) ? -1.f : 0.f);
    float D = sgn * acosf(cosD);
    cD = cosf(D); sD = sinf(D);
  }
  int n = t/3, col = t - n*3;
  bbe[(size_t)n*104 + col] = cD;
  bbe[(size_t)n*104 + 3 + col] = sD;
}

// ---------------- KNN: wave per query, window-seeded exact top-30 ----------------
__global__ __launch_bounds__(256) void k_knn(const float* __restrict__ xs,
        const float* __restrict__ ys, const float* __restrict__ zs, int* __restrict__ src){
  __shared__ float sd[4][32];
  __shared__ int   si[4][32];
  int w = threadIdx.x >> 6, lane = threadIdx.x & 63;
  int n = blockIdx.x*4 + w;
  float qx = xs[n], qy = ys[n], qz = zs[n];
  if (lane >= 30 && lane < 32){ sd[w][lane] = INFINITY; si[w][lane] = 0; }

  int w0 = n - 32; if (w0 < 0) w0 = 0; if (w0 > NN-64) w0 = NN-64;
  int idx = w0 + lane;
  {
    float dx = qx - xs[idx], dy = qy - ys[idx], dz = qz - zs[idx];
    float d2 = dx*dx + dy*dy + dz*dz;
    if (idx == n) d2 = INFINITY;
    #pragma unroll
    for (int k = 2; k <= 64; k <<= 1){
      #pragma unroll
      for (int jj = k>>1; jj >= 1; jj >>= 1){
        float od = __shfl_xor(d2, jj);
        int   oi = __shfl_xor(idx, jj);
        bool up      = ((lane & k) == 0);
        bool lower   = ((lane & jj) == 0);
        bool takeMin = (up == lower);
        bool mless   = (d2 < od) || (d2 == od && idx < oi);
        if (mless != takeMin){ d2 = od; idx = oi; }
      }
    }
    if (lane < 30){ sd[w][lane] = d2; si[w][lane] = idx; }
  }
  float thr = sd[w][29];

  for (int s = 0; s < NN/64; ++s){
    int j = s*64 + lane;
    float dx = __fsub_rn(qx, xs[j]);
    float dy = __fsub_rn(qy, ys[j]);
    float dz = __fsub_rn(qz, zs[j]);
    float d2 = __fadd_rn(__fadd_rn(__fmul_rn(dx,dx),__fmul_rn(dy,dy)),__fmul_rn(dz,dz));
    if (j == n) d2 = INFINITY;
    if (j >= w0 && j < w0+64) d2 = INFINITY;
    unsigned long long bal = __ballot(d2 < thr);
    if (bal){
      while (bal){
        int b = __ffsll((unsigned long long)bal) - 1;
        bal &= bal - 1ull;
        float vd = __shfl(d2, b);
        int vj = s*64 + b;
        float dl = 0.f; int il = 0; bool keep = true;
        if (lane < 30){ dl = sd[w][lane]; il = si[w][lane]; keep = (dl <= vd); }
        unsigned long long km = __ballot(lane < 30 && keep);
        int pos = __popcll(km);
        if (lane < 30 && !keep){ sd[w][lane+1] = dl; si[w][lane+1] = il; }
        if (lane == pos){ sd[w][lane] = vd; si[w][lane] = vj; }
      }
      thr = sd[w][29];
    }
  }
  if (lane < 30) src[(size_t)n*KK + lane] = si[w][lane];
}

// ---------------- edge features: rbf(16) + pos_emb(16) ----------------
__global__ void k_edgefeat(const int* __restrict__ src, const float* __restrict__ xs,
        const float* __restrict__ ys, const float* __restrict__ zs, float* __restrict__ ef){
  int e = blockIdx.x*blockDim.x + threadIdx.x;
  if (e >= NE) return;
  int n = e / KK;
  int j = src[e];
  float vx = xs[j]-xs[n], vy = ys[j]-ys[n], vz = zs[j]-zs[n];
  float dist = sqrtf(vx*vx + vy*vy + vz*vz + EPSF);
  float* o = ef + (size_t)e*32;
  #pragma unroll
  for (int m=0;m<16;++m){
    float mu = (float)m * (20.f/15.f);
    float q = (dist - mu) / 1.25f;
    o[m] = expf(-q*q);
  }
  float d = (float)(j - n);
  const float Cf = -0.5756462732485115f;   // -ln(1e4)/16
  #pragma unroll
  for (int fi=0; fi<8; ++fi){
    float fr = expf((float)(2*fi) * Cf);
    float ang = d * fr;
    o[16+fi] = cosf(ang);
    o[24+fi] = sinf(ang);
  }
}

// ---------------- generic f32 GEMM (R2 core): C[M,Nc] = act(A@B) (+C if beta) ----
// A row r -> A + (r/arpg)*agst + (r%arpg)*arst + aoff  (arpg in {1,3})
// BSEL: 0 = B1[kk*Nc+c]; 1 = [Wa_src|Wa_dst|Wv0] pack (Nc=80, B1=Wa[160x8] B2=Wv0[64x64]);
//       2 = [eW_src|eW_dst] pack (Nc=64, B1=eW[160x32 used rows 0..127])
// ACT: 0 none, 2 = swiglu across the 4 s-rows of each node (M%64==0, rows=4n+s)
template<int K, int ACT, int BSEL>
__global__ __launch_bounds__(256) void k_gemm(const float* __restrict__ A,
        const float* __restrict__ B1, const float* __restrict__ B2,
        const float* __restrict__ bias, float* __restrict__ C,
        int M, int Nc, int arpg, int agst, int arst, int aoff, int beta){
  __shared__ float As[64*(K+1)];
  __shared__ alignas(16) float Bs[K*64];
  int tid = threadIdx.x, tm = blockIdx.x, tn = blockIdx.y;
  for (int i = tid; i < K*64; i += 256){
    int kk = i >> 6, cl = i & 63;
    int c = tn*64 + cl;
    float v = 0.f;
    if (c < Nc){
      if (BSEL == 0) v = B1[kk*Nc + c];
      else if (BSEL == 1) v = (c<8) ? B1[kk*8+c] : ((c<16) ? B1[(64+kk)*8 + (c-8)] : B2[kk*64 + (c-16)]);
      else v = (c<32) ? B1[kk*32 + c] : B1[(64+kk)*32 + (c-32)];
    }
    Bs[i] = v;
  }
  for (int i = tid; i < 64*K; i += 256){
    int rl = i / K, kk = i - rl*K;
    int r = tm*64 + rl;
    float v = 0.f;
    if (r < M){
      const float* ap;
      if (arpg == 1) ap = A + (size_t)r*agst + aoff;
      else { int g = r/3; int wr = r - g*3; ap = A + (size_t)g*agst + wr*arst + aoff; }
      v = ap[kk];
    }
    As[rl*(K+1) + kk] = v;
  }
  __syncthreads();
  int tx = tid & 15, ty = tid >> 4;
  float acc[4][4] = {};
  for (int kk = 0; kk < K; ++kk){
    float4 b4 = *reinterpret_cast<const float4*>(&Bs[kk*64 + tx*4]);
    #pragma unroll
    for (int rr = 0; rr < 4; ++rr){
      float a = As[(ty*4+rr)*(K+1) + kk];
      acc[rr][0] += a*b4.x; acc[rr][1] += a*b4.y; acc[rr][2] += a*b4.z; acc[rr][3] += a*b4.w;
    }
  }
  if (ACT == 2){
    int r0 = tm*64 + ty*4;
    #pragma unroll
    for (int cc = 0; cc < 4; ++cc){
      int c = tn*64 + tx*4 + cc;
      if (c >= Nc) continue;
      float t0 = acc[0][cc];
      float g = 1.f/(1.f + expf(-t0));
      C[(size_t)(r0+0)*Nc + c] = t0*g;
      C[(size_t)(r0+1)*Nc + c] = acc[1][cc]*g;
      C[(size_t)(r0+2)*Nc + c] = acc[2][cc]*g;
      C[(size_t)(r0+3)*Nc + c] = acc[3][cc]*g;
    }
  } else {
    #pragma unroll
    for (int rr = 0; rr < 4; ++rr){
      int r = tm*64 + ty*4 + rr;
      if (r >= M) continue;
      #pragma unroll
      for (int cc = 0; cc < 4; ++cc){
        int c = tn*64 + tx*4 + cc;
        if (c >= Nc) continue;
        float v = acc[rr][cc];
        if (bias) v += bias[c];
        size_t ci = (size_t)r*Nc + c;
        if (beta) v += C[ci];
        C[ci] = v;
      }
    }
  }
}

// ---------------- fused attention: inline alpha-edge logits + softmax + gather ----------------
__global__ __launch_bounds__(256) void k_attn(const int* __restrict__ src,
        const float* __restrict__ NF, const float* __restrict__ V1,
        const float* __restrict__ ef, const float* __restrict__ WaE, float* __restrict__ o){
  int w = threadIdx.x >> 6, lane = threadIdx.x & 63;
  int n = blockIdx.x*4 + w;
  int h = lane >> 3, q = lane & 7;
  float w0 = WaE[(q*4+0)*8 + h];
  float w1 = WaE[(q*4+1)*8 + h];
  float w2 = WaE[(q*4+2)*8 + h];
  float w3 = WaE[(q*4+3)*8 + h];
  const int* sk = src + (size_t)n*KK;
  int myj = (lane < KK) ? sk[lane] : 0;
  float a2 = NF[(size_t)n*80 + 8 + h];
  float m = -INFINITY, s = 0.f, o0=0.f, o1=0.f, o2=0.f, o3=0.f;
  for (int k = 0; k < KK; ++k){
    int j = __shfl(myj, k);
    float4 e4 = *reinterpret_cast<const float4*>(ef + ((size_t)n*KK + k)*32 + q*4);
    float val = e4.x*w0 + e4.y*w1 + e4.z*w2 + e4.w*w3;
    val += __shfl_xor(val, 1);
    val += __shfl_xor(val, 2);
    val += __shfl_xor(val, 4);
    float l = val + NF[(size_t)j*80 + h] + a2;
    l = (l >= 0.f) ? l : 0.2f*l;
    float mn = fmaxf(m, l);
    float f = expf(m - mn);
    float pp = expf(l - mn);
    s = s*f + pp;
    const float* v1p = V1 + (size_t)j*192;
    o0 = o0*f + pp*NF[(size_t)j*80 + 16 + lane];
    o1 = o1*f + pp*v1p[lane];
    o2 = o2*f + pp*v1p[64+lane];
    o3 = o3*f + pp*v1p[128+lane];
    m = mn;
  }
  float inv = 1.f/s;
  float* op = o + (size_t)n*256;
  op[lane] = o0*inv; op[64+lane] = o1*inv; op[128+lane] = o2*inv; op[192+lane] = o3*inv;
}

// ---------------- fused so3: gate MLP + gather-aggregate, one node per block ----------------
// H[k][h] = silu(ef_row_k @ Wrad + brad); g0/g1 = H @ Wgate halves;
// out0 = sum_k g0*M0[j_k]; out_s = sum_k g1*M1[j_k][s]; all /sqrt(30).
template<int C>   // 32 (eb) or 91 (oa)
__global__ __launch_bounds__(256) void k_so3fused(const int* __restrict__ src,
        const float* __restrict__ ef, const float* __restrict__ Wrad,
        const float* __restrict__ brad, const float* __restrict__ Wgate,
        const float* __restrict__ M0, const float* __restrict__ M1,
        float* __restrict__ out, int nstr, int sstr){
  constexpr int KG  = 256 / C;            // 8 / 2
  constexpr int KPT = (KK + KG - 1) / KG; // 4 / 15
  __shared__ float efs[KK*32];
  __shared__ float Wr[32*64];
  __shared__ float Hs[KK*64];
  __shared__ float Wg[64*(C+1)];
  __shared__ float part[3*256];
  __shared__ int   js[KK];
  int n = blockIdx.x, tid = threadIdx.x;
  for (int i = tid; i < KK*32; i += 256) efs[i] = ef[(size_t)n*KK*32 + i];
  for (int i = tid; i < 2048;  i += 256) Wr[i]  = Wrad[i];
  if (tid < KK) js[tid] = src[(size_t)n*KK + tid];
  __syncthreads();
  for (int i = tid; i < KK*64; i += 256){
    int k = i >> 6, h = i & 63;
    float a = brad[h];
    const float* er = efs + k*32;
    #pragma unroll
    for (int m = 0; m < 32; ++m) a += er[m]*Wr[m*64 + h];
    Hs[i] = a/(1.f + expf(-a));
  }
  __syncthreads();
  int c = tid % C, kg = tid / C;
  bool act = (kg < KG);
  // phase A: scalar channel
  for (int i = tid; i < 64*C; i += 256){ int m = i/C, cc = i - m*C; Wg[m*(C+1)+cc] = Wgate[m*2*C + cc]; }
  __syncthreads();
  if (act){
    float a0 = 0.f;
    for (int t = 0; t < KPT; ++t){
      int k = kg*KPT + t;
      if (k < KK){
        const float* hr = Hs + k*64;
        float g = 0.f;
        #pragma unroll
        for (int m = 0; m < 64; ++m) g += hr[m]*Wg[m*(C+1) + c];
        a0 += g * M0[(size_t)js[k]*C + c];
      }
    }
    part[kg*C + c] = a0;
  }
  __syncthreads();
  const float IS = 0.18257418583505536f;  // 1/sqrt(30)
  if (tid < C){
    float s = 0.f;
    for (int g = 0; g < KG; ++g) s += part[g*C + tid];
    out[(size_t)n*nstr + tid] = s*IS;
  }
  __syncthreads();
  // phase B: vector channels
  for (int i = tid; i < 64*C; i += 256){ int m = i/C, cc = i - m*C; Wg[m*(C+1)+cc] = Wgate[m*2*C + C + cc]; }
  __syncthreads();
  if (act){
    float a1 = 0.f, a2 = 0.f, a3 = 0.f;
    for (int t = 0; t < KPT; ++t){
      int k = kg*KPT + t;
      if (k < KK){
        const float* hr = Hs + k*64;
        float g = 0.f;
        #pragma unroll
        for (int m = 0; m < 64; ++m) g += hr[m]*Wg[m*(C+1) + c];
        const float* m1p = M1 + (size_t)js[k]*3*C;
        a1 += g*m1p[c]; a2 += g*m1p[C+c]; a3 += g*m1p[2*C+c];
      }
    }
    part[kg*C + c] = a1;
    part[KG*C + kg*C + c] = a2;
    part[2*KG*C + kg*C + c] = a3;
  }
  __syncthreads();
  if (tid < C){
    float s1=0.f, s2=0.f, s3=0.f;
    for (int g = 0; g < KG; ++g){
      s1 += part[g*C + tid];
      s2 += part[KG*C + g*C + tid];
      s3 += part[2*KG*C + g*C + tid];
    }
    float* ob = out + (size_t)n*nstr + tid;
    ob[sstr] = s1*IS; ob[2*sstr] = s2*IS; ob[3*sstr] = s3*IS;
  }
}

// ---------------- latent copy into res cols 32..63 ----------------
__global__ void k_lat(const float* __restrict__ latent, float* __restrict__ res){
  int t = blockIdx.x*blockDim.x + threadIdx.x;
  if (t >= NN*128) return;
  int n = t >> 7, rc = t & 127, s = rc >> 5, c = rc & 31;
  res[(size_t)n*256 + s*64 + 32 + c] = latent[t];
}

// ---------------- edge feature update (fused ef@eW_e matvec, in-place) ----------------
__global__ __launch_bounds__(256) void k_edgeout(const int* __restrict__ src,
        const float* __restrict__ eWe, const float* __restrict__ EE,
        const float* __restrict__ ebv, float* __restrict__ ef){
  __shared__ float ws[32*32];
  __shared__ float es[8*32];
  int tid = threadIdx.x;
  size_t e0 = (size_t)blockIdx.x*8;
  for (int i = tid; i < 1024; i += 256) ws[i] = eWe[i];
  es[tid] = ef[e0*32 + tid];
  __syncthreads();
  int le = tid >> 5, c = tid & 31;
  size_t e = e0 + le;
  int n = (int)(e / KK);
  int j = src[e];
  float acc = ebv[c] + EE[(size_t)j*64 + c] + EE[(size_t)n*64 + 32 + c];
  const float* er = es + le*32;
  #pragma unroll
  for (int kk = 0; kk < 32; ++kk) acc += er[kk]*ws[kk*32 + c];
  ef[e*32 + c] = tanhf(acc);
}

// ---------------- head: LN + seq logits + transpose decoded ----------------
__global__ __launch_bounds__(128) void k_head(const float* __restrict__ atoms,
        const float* __restrict__ ln_g, const float* __restrict__ ln_b,
        const float* __restrict__ W_seq, const float* __restrict__ b_seq, float* __restrict__ out){
  __shared__ float red[128];
  __shared__ float nrm[91];
  __shared__ float lg[20];
  int n = blockIdx.x, t = threadIdx.x;
  const float* inv = atoms + (size_t)n*364;
  float x = (t < 91) ? inv[t] : 0.f;
  red[t] = x; __syncthreads();
  for (int off=64; off>=1; off>>=1){ if (t<off) red[t]+=red[t+off]; __syncthreads(); }
  float mu = red[0] / 91.f;
  __syncthreads();
  float d = x - mu;
  red[t] = (t<91) ? d*d : 0.f; __syncthreads();
  for (int off=64; off>=1; off>>=1){ if (t<off) red[t]+=red[t+off]; __syncthreads(); }
  float var = red[0] / 91.f;
  __syncthreads();
  if (t < 91) nrm[t] = (x - mu)/sqrtf(var + 1e-5f) * ln_g[t] + ln_b[t];
  __syncthreads();
  if (t < 20){
    float acc = b_seq[t];
    for (int c=0;c<91;++c) acc += nrm[c]*W_seq[c*20+t];
    lg[t] = acc;
  }
  __syncthreads();
  if (t == 0){
    float mx = lg[0];
    for (int i=1;i<20;++i) mx = fmaxf(mx, lg[i]);
    float s = 0.f;
    for (int i=0;i<20;++i) s += expf(lg[i]-mx);
    red[0] = mx + logf(s);
  }
  __syncthreads();
  float lse = red[0];
  if (t < 20) out[(size_t)NN*273 + (size_t)n*20 + t] = lg[t] - lse;
  for (int idx = t; idx < 273; idx += 128){
    int c = idx/3, i = idx - c*3;
    out[(size_t)n*273 + idx] = atoms[(size_t)n*364 + (1+i)*91 + c];
  }
}

// ---------------- host dispatch ----------------
static void gemm(hipStream_t st, int K, int act, int bsel, const float* A,
                 const float* B1, const float* B2, const float* bias, float* C,
                 int M, int Nc, int arpg, int agst, int arst, int aoff, int beta){
  dim3 g((M+63)/64, (Nc+63)/64), b(256);
  if (K == 26){
    k_gemm<26,0,0><<<g,b,0,st>>>(A,B1,B2,bias,C,M,Nc,arpg,agst,arst,aoff,beta);
  } else if (K == 32){
    if (act == 2) k_gemm<32,2,0><<<g,b,0,st>>>(A,B1,B2,bias,C,M,Nc,arpg,agst,arst,aoff,beta);
    else          k_gemm<32,0,0><<<g,b,0,st>>>(A,B1,B2,bias,C,M,Nc,arpg,agst,arst,aoff,beta);
  } else {
    if (act == 2)        k_gemm<64,2,0><<<g,b,0,st>>>(A,B1,B2,bias,C,M,Nc,arpg,agst,arst,aoff,beta);
    else if (bsel == 1)  k_gemm<64,0,1><<<g,b,0,st>>>(A,B1,B2,bias,C,M,Nc,arpg,agst,arst,aoff,beta);
    else if (bsel == 2)  k_gemm<64,0,2><<<g,b,0,st>>>(A,B1,B2,bias,C,M,Nc,arpg,agst,arst,aoff,beta);
    else                 k_gemm<64,0,0><<<g,b,0,st>>>(A,B1,B2,bias,C,M,Nc,arpg,agst,arst,aoff,beta);
  }
}

extern "C" void kernel_launch(void* const* d_in, const int* in_sizes, int n_in,
                              void* d_out, int out_size, void* d_ws, size_t ws_size,
                              hipStream_t stream){
  (void)in_sizes; (void)n_in; (void)out_size;
  if (ws_size < WS_NEEDED) return;

  const float* bb      = (const float*)d_in[0];
  const float* latent  = (const float*)d_in[2];
  const float* eb_Wrad = (const float*)d_in[3];
  const float* eb_brad = (const float*)d_in[4];
  const float* eb_Wgate= (const float*)d_in[5];
  const float* eb_W0   = (const float*)d_in[6];
  const float* eb_W1   = (const float*)d_in[7];
  const float* t_Walpha= (const float*)d_in[8];
  const float* t_Wv0   = (const float*)d_in[9];
  const float* t_Wv1   = (const float*)d_in[10];
  const float* t_Wo    = (const float*)d_in[11];
  const float* t_Wf1   = (const float*)d_in[12];
  const float* t_Wf2   = (const float*)d_in[13];
  const float* e_W     = (const float*)d_in[14];
  const float* e_b     = (const float*)d_in[15];
  const float* p_Walpha= (const float*)d_in[16];
  const float* p_Wv0   = (const float*)d_in[17];
  const float* p_Wv1   = (const float*)d_in[18];
  const float* p_Wo    = (const float*)d_in[19];
  const float* p_Wf1   = (const float*)d_in[20];
  const float* p_Wf2   = (const float*)d_in[21];
  const float* oa_Wrad = (const float*)d_in[22];
  const float* oa_brad = (const float*)d_in[23];
  const float* oa_Wgate= (const float*)d_in[24];
  const float* oa_W0   = (const float*)d_in[25];
  const float* oa_W1   = (const float*)d_in[26];
  const float* ln_g    = (const float*)d_in[27];
  const float* ln_b    = (const float*)d_in[28];
  const float* W_seq   = (const float*)d_in[29];
  const float* b_seq   = (const float*)d_in[30];

  char* w = (char*)d_ws;
  int*   src = (int*)  (w + O_SRC);
  float* xs  = (float*)(w + O_XS);
  float* ys  = (float*)(w + O_YS);
  float* zs  = (float*)(w + O_ZS);
  float* bbe = (float*)(w + O_BBE);
  float* res = (float*)(w + O_RES);
  float* p   = (float*)(w + O_P);
  float* ef  = (float*)(w + O_EF);
  float* NF  = (float*)(w + O_NF);
  float* V1  = (float*)(w + O_V1);
  float* o   = (float*)(w + O_O);
  float* EE  = (float*)(w + O_EE);
  float* M0e = (float*)(w + O_M0E);
  float* M1e = (float*)(w + O_M1E);
  float* M0o = (float*)(w + O_M0O);
  float* M1o = (float*)(w + O_M1O);
  float* atm = (float*)(w + O_ATM);

  // ---- geometry ----
  k_prep <<<(NN+255)/256, 256, 0, stream>>>(bb, xs, ys, zs, bbe);
  k_dihed<<<(3*NN+255)/256, 256, 0, stream>>>(bb, bbe);
  k_knn  <<<NN/4, 256, 0, stream>>>(xs, ys, zs, src);
  k_edgefeat<<<(NE+255)/256, 256, 0, stream>>>(src, xs, ys, zs, ef);

  // ---- eb so3_conv -> res[:,:,0:32] ----
  gemm(stream, 26,0,0, bbe, eb_W0, nullptr, nullptr, M0e, NN,   32, 1,104, 0, 0, 0);
  gemm(stream, 26,0,0, bbe, eb_W1, nullptr, nullptr, M1e, 3*NN, 32, 3,104,26,26, 0);
  k_so3fused<32><<<NN, 256, 0, stream>>>(src, ef, eb_Wrad, eb_brad, eb_Wgate, M0e, M1e, res, 256, 64);
  k_lat<<<(NN*128+255)/256, 256, 0, stream>>>(latent, res);

  // ---- transformer layers ----
  for (int L=0; L<4; ++L){
    const float* Wa  = t_Walpha + (size_t)L*160*8;
    const float* Wv0 = t_Wv0 + (size_t)L*64*64;
    const float* Wv1 = t_Wv1 + (size_t)L*64*64;
    const float* Wo  = t_Wo  + (size_t)L*64*64;
    const float* Wf1 = t_Wf1 + (size_t)L*64*64;
    const float* Wf2 = t_Wf2 + (size_t)L*64*64;
    const float* eWl = e_W   + (size_t)L*160*32;
    const float* ebl = e_b   + (size_t)L*32;
    gemm(stream, 64,0,1, res, Wa, Wv0, nullptr, NF, NN,   80, 1,256, 0, 0, 0);
    gemm(stream, 64,0,0, res, Wv1, nullptr, nullptr, V1, 3*NN, 64, 3,256,64,64, 0);
    k_attn<<<NN/4, 256, 0, stream>>>(src, NF, V1, ef, Wa + 128*8, o);
    gemm(stream, 64,0,0, o,   Wo,  nullptr, nullptr, res, 4*NN, 64, 1,64,0,0, 1);
    gemm(stream, 64,2,0, res, Wf1, nullptr, nullptr, o,   4*NN, 64, 1,64,0,0, 0);
    gemm(stream, 64,0,0, o,   Wf2, nullptr, nullptr, res, 4*NN, 64, 1,64,0,0, 1);
    gemm(stream, 64,0,2, res, eWl, nullptr, nullptr, EE,  NN,   64, 1,256,0,0, 0);
    k_edgeout<<<NE/8, 256, 0, stream>>>(src, eWl + 128*32, EE, ebl, ef);
  }

  // ---- p = attn(res) + ffn ----
  gemm(stream, 64,0,1, res, p_Walpha, p_Wv0, nullptr, NF, NN,   80, 1,256, 0, 0, 0);
  gemm(stream, 64,0,0, res, p_Wv1, nullptr, nullptr, V1, 3*NN, 64, 3,256,64,64, 0);
  k_attn<<<NN/4, 256, 0, stream>>>(src, NF, V1, ef, p_Walpha + 128*8, o);
  gemm(stream, 64,0,0, o, p_Wo,  nullptr, nullptr, p, 4*NN, 32, 1,64,0,0, 0);
  gemm(stream, 32,2,0, p, p_Wf1, nullptr, nullptr, o, 4*NN, 32, 1,32,0,0, 0);
  gemm(stream, 32,0,0, o, p_Wf2, nullptr, nullptr, p, 4*NN, 32, 1,32,0,0, 1);

  // ---- oa so3_conv -> atoms ----
  gemm(stream, 32,0,0, p, oa_W0, nullptr, nullptr, M0o, NN,   91, 1,128, 0, 0, 0);
  gemm(stream, 32,0,0, p, oa_W1, nullptr, nullptr, M1o, 3*NN, 91, 3,128,32,32, 0);
  k_so3fused<91><<<NN, 256, 0, stream>>>(src, ef, oa_Wrad, oa_brad, oa_Wgate, M0o, M1o, atm, 364, 91);

  // ---- head ----
  k_head<<<NN, 128, 0, stream>>>(atm, ln_g, ln_b, W_seq, b_seq, (float*)d_out);
}

// Round 7
// 1370.774 us; speedup vs baseline: 3.2937x; 1.0201x over previous
//
#include <hip/hip_runtime.h>
#include <math.h>

// LatentDecoder on MI355X. All f32. Rotations R eliminated (orthogonal, cancel
// around per-channel gates). Per-edge linear maps commuted to per-node + gather.
// R1: KNN window-seeded threshold scan (exact).
// R2: alpha-edge logits fused into k_attn; ef@eW_e fused into k_edgeout.
// R3 (reverted): transposed-As GEMM -> VGPR 256 + LDS write conflicts.
// R4: fused gate MLP+gather (k_so3fused); swiglu in GEMM epilogue; no repack.
// R5: - GEMM inner: float4-across-kk for As AND Bs (8 b128 / 64 FMA), row-major
//       As staging kept (conflict-free writes), stride KP+4, unroll 2.
//     - so3fused gate: register-tiled mini-GEMM (4k/2k x 4c), Hs stride 68,
//       aligned float4 M0/M1 gather (M0o/M1o GEMMs write ldc=92).
//     - k_lat folded into so3fused<32> epilogue.
// R6/R7: identical to R5 (benches timed out on GPU acquisition — no data).

#define NN 8192
#define KK 30
#define NE (NN*KK)      // 245760
#define EPSF 1e-7f

// ---------------- workspace layout (bytes) ----------------
static const size_t O_SRC = 0;                  // int [NN*30]
static const size_t O_XS  = 1ull<<20;
static const size_t O_YS  = O_XS + (size_t)NN*4;
static const size_t O_ZS  = O_XS + (size_t)NN*8;
static const size_t O_BBE = 2ull<<20;           // float[NN*4*26]
static const size_t O_RES = 6ull<<20;           // float[NN*4*64]
static const size_t O_P   = 15ull<<20;          // float[NN*4*32]
static const size_t O_EF  = 20ull<<20;          // float[NE*32]    (ends 50MB)
// layer-phase scratch:
static const size_t O_NF  = 52ull<<20;          // float[NN*80]
static const size_t O_V1  = 55ull<<20;          // float[NN*3*64]
static const size_t O_O   = 62ull<<20;          // float[NN*4*64]
static const size_t O_EE  = 71ull<<20;          // float[NN*64]
// eb so3 phase (aliases layer scratch):
static const size_t O_M0E = 52ull<<20;          // float[NN*32]
static const size_t O_M1E = 54ull<<20;          // float[NN*3*32]
// oa so3 phase (aliases layer scratch + res/p, all dead by then):
static const size_t O_M0O = 52ull<<20;          // float[NN*92]    (ldc-padded)
static const size_t O_M1O = 56ull<<20;          // float[NN*3*92]  (ends 65MB)
static const size_t O_ATM = 6ull<<20;           // float[NN*4*91]
static const size_t WS_NEEDED = 80ull<<20;

// ---------------- small device helpers ----------------
__device__ __forceinline__ float nn0(float v){ return (v != v) ? 0.f : v; }
__device__ __forceinline__ void norm3(float& x, float& y, float& z){
  float s = sqrtf(x*x + y*y + z*z + EPSF);
  x /= s; y /= s; z /= s;
}

// ---------------- prep ----------------
__global__ void k_prep(const float* __restrict__ bb, float* __restrict__ xs,
                       float* __restrict__ ys, float* __restrict__ zs,
                       float* __restrict__ bbe){
  int n = blockIdx.x*blockDim.x + threadIdx.x;
  if (n >= NN) return;
  const float* bn = bb + (size_t)n*12;
  float a0x=bn[0],a0y=bn[1],a0z=bn[2];
  float cax=bn[3],cay=bn[4],caz=bn[5];
  float a2x=bn[6],a2y=bn[7],a2z=bn[8];
  float a3x=bn[9],a3y=bn[10],a3z=bn[11];
  xs[n]=cax; ys[n]=cay; zs[n]=caz;
  float v[7][3];
  v[0][0]=a0x-cax; v[0][1]=a0y-cay; v[0][2]=a0z-caz;
  v[1][0]=0.f;     v[1][1]=0.f;     v[1][2]=0.f;
  v[2][0]=a2x-cax; v[2][1]=a2y-cay; v[2][2]=a2z-caz;
  v[3][0]=a3x-cax; v[3][1]=a3y-cay; v[3][2]=a3z-caz;
  if (n < NN-1){
    float fx=bb[(size_t)(n+1)*12+3]-cax, fy=bb[(size_t)(n+1)*12+4]-cay, fz=bb[(size_t)(n+1)*12+5]-caz;
    norm3(fx,fy,fz); v[4][0]=fx; v[4][1]=fy; v[4][2]=fz;
  } else { v[4][0]=v[4][1]=v[4][2]=0.f; }
  if (n > 0){
    float gx=bb[(size_t)(n-1)*12+3]-cax, gy=bb[(size_t)(n-1)*12+4]-cay, gz=bb[(size_t)(n-1)*12+5]-caz;
    norm3(gx,gy,gz); v[5][0]=gx; v[5][1]=gy; v[5][2]=gz;
  } else { v[5][0]=v[5][1]=v[5][2]=0.f; }
  {
    float bx=cax-a0x, by=cay-a0y, bz=caz-a0z;
    float cx=a2x-cax, cy=a2y-cay, cz=a2z-caz;
    float ax = by*cz - bz*cy, ay = bz*cx - bx*cz, az = bx*cy - by*cx;
    v[6][0] = -0.58273431f*ax + 0.56802827f*bx - 0.54067466f*cx;
    v[6][1] = -0.58273431f*ay + 0.56802827f*by - 0.54067466f*cy;
    v[6][2] = -0.58273431f*az + 0.56802827f*bz - 0.54067466f*cz;
  }
  float* be = bbe + (size_t)n*104;
  #pragma unroll
  for (int c=6;c<26;++c) be[c]=0.f;
  #pragma unroll
  for (int s=0;s<3;++s){
    float* br = be + 26*(1+s);
    #pragma unroll
    for (int c=0;c<26;++c) br[c] = (c<7) ? nn0(v[c][s]) : 0.f;
  }
}

// ---------------- dihedrals ----------------
__global__ void k_dihed(const float* __restrict__ bb, float* __restrict__ bbe){
  int t = blockIdx.x*blockDim.x + threadIdx.x;
  if (t >= 3*NN) return;
  float cD = 1.f, sD = 0.f;
  if (t >= 1 && t < 3*NN-2){
    int i = t-1;
    float p[4][3];
    #pragma unroll
    for (int m=0;m<4;++m){
      int a = i+m; int rn = a/3, ra = a - rn*3;
      const float* q = bb + (size_t)(rn*4 + ra)*3;
      p[m][0]=q[0]; p[m][1]=q[1]; p[m][2]=q[2];
    }
    float u2x=p[1][0]-p[0][0], u2y=p[1][1]-p[0][1], u2z=p[1][2]-p[0][2];
    float u1x=p[2][0]-p[1][0], u1y=p[2][1]-p[1][1], u1z=p[2][2]-p[1][2];
    float u0x=p[3][0]-p[2][0], u0y=p[3][1]-p[2][1], u0z=p[3][2]-p[2][2];
    norm3(u2x,u2y,u2z); norm3(u1x,u1y,u1z); norm3(u0x,u0y,u0z);
    float n2x=u2y*u1z-u2z*u1y, n2y=u2z*u1x-u2x*u1z, n2z=u2x*u1y-u2y*u1x;
    float n1x=u1y*u0z-u1z*u0y, n1y=u1z*u0x-u1x*u0z, n1z=u1x*u0y-u1y*u0x;
    norm3(n2x,n2y,n2z); norm3(n1x,n1y,n1z);
    float cosD = n2x*n1x + n2y*n1y + n2z*n1z;
    const float lo = (float)(-1.0 + 1e-7), hi = (float)(1.0 - 1e-7);
    cosD = fminf(fmaxf(cosD, lo), hi);
    float sg = u2x*n1x + u2y*n1y + u2z*n1z;
    float sgn = (sg > 0.f) ? 1.f : ((sg < 0.f) ? -1.f : 0.f);
    float D = sgn * acosf(cosD);
    cD = cosf(D); sD = sinf(D);
  }
  int n = t/3, col = t - n*3;
  bbe[(size_t)n*104 + col] = cD;
  bbe[(size_t)n*104 + 3 + col] = sD;
}

// ---------------- KNN: wave per query, window-seeded exact top-30 ----------------
__global__ __launch_bounds__(256) void k_knn(const float* __restrict__ xs,
        const float* __restrict__ ys, const float* __restrict__ zs, int* __restrict__ src){
  __shared__ float sd[4][32];
  __shared__ int   si[4][32];
  int w = threadIdx.x >> 6, lane = threadIdx.x & 63;
  int n = blockIdx.x*4 + w;
  float qx = xs[n], qy = ys[n], qz = zs[n];
  if (lane >= 30 && lane < 32){ sd[w][lane] = INFINITY; si[w][lane] = 0; }

  int w0 = n - 32; if (w0 < 0) w0 = 0; if (w0 > NN-64) w0 = NN-64;
  int idx = w0 + lane;
  {
    float dx = qx - xs[idx], dy = qy - ys[idx], dz = qz - zs[idx];
    float d2 = dx*dx + dy*dy + dz*dz;
    if (idx == n) d2 = INFINITY;
    #pragma unroll
    for (int k = 2; k <= 64; k <<= 1){
      #pragma unroll
      for (int jj = k>>1; jj >= 1; jj >>= 1){
        float od = __shfl_xor(d2, jj);
        int   oi = __shfl_xor(idx, jj);
        bool up      = ((lane & k) == 0);
        bool lower   = ((lane & jj) == 0);
        bool takeMin = (up == lower);
        bool mless   = (d2 < od) || (d2 == od && idx < oi);
        if (mless != takeMin){ d2 = od; idx = oi; }
      }
    }
    if (lane < 30){ sd[w][lane] = d2; si[w][lane] = idx; }
  }
  float thr = sd[w][29];

  for (int s = 0; s < NN/64; ++s){
    int j = s*64 + lane;
    float dx = __fsub_rn(qx, xs[j]);
    float dy = __fsub_rn(qy, ys[j]);
    float dz = __fsub_rn(qz, zs[j]);
    float d2 = __fadd_rn(__fadd_rn(__fmul_rn(dx,dx),__fmul_rn(dy,dy)),__fmul_rn(dz,dz));
    if (j == n) d2 = INFINITY;
    if (j >= w0 && j < w0+64) d2 = INFINITY;
    unsigned long long bal = __ballot(d2 < thr);
    if (bal){
      while (bal){
        int b = __ffsll((unsigned long long)bal) - 1;
        bal &= bal - 1ull;
        float vd = __shfl(d2, b);
        int vj = s*64 + b;
        float dl = 0.f; int il = 0; bool keep = true;
        if (lane < 30){ dl = sd[w][lane]; il = si[w][lane]; keep = (dl <= vd); }
        unsigned long long km = __ballot(lane < 30 && keep);
        int pos = __popcll(km);
        if (lane < 30 && !keep){ sd[w][lane+1] = dl; si[w][lane+1] = il; }
        if (lane == pos){ sd[w][lane] = vd; si[w][lane] = vj; }
      }
      thr = sd[w][29];
    }
  }
  if (lane < 30) src[(size_t)n*KK + lane] = si[w][lane];
}

// ---------------- edge features: rbf(16) + pos_emb(16) ----------------
__global__ void k_edgefeat(const int* __restrict__ src, const float* __restrict__ xs,
        const float* __restrict__ ys, const float* __restrict__ zs, float* __restrict__ ef){
  int e = blockIdx.x*blockDim.x + threadIdx.x;
  if (e >= NE) return;
  int n = e / KK;
  int j = src[e];
  float vx = xs[j]-xs[n], vy = ys[j]-ys[n], vz = zs[j]-zs[n];
  float dist = sqrtf(vx*vx + vy*vy + vz*vz + EPSF);
  float* o = ef + (size_t)e*32;
  #pragma unroll
  for (int m=0;m<16;++m){
    float mu = (float)m * (20.f/15.f);
    float q = (dist - mu) / 1.25f;
    o[m] = expf(-q*q);
  }
  float d = (float)(j - n);
  const float Cf = -0.5756462732485115f;   // -ln(1e4)/16
  #pragma unroll
  for (int fi=0; fi<8; ++fi){
    float fr = expf((float)(2*fi) * Cf);
    float ang = d * fr;
    o[16+fi] = cosf(ang);
    o[24+fi] = sinf(ang);
  }
}

// ---------------- generic f32 GEMM: C[M,(ldc)Nc] = act(A@B) (+C if beta) ----
// Row-major As staged (conflict-free writes), float4 reads across kk for BOTH
// As and Bs: 8 b128 per 64 FMA. kk summation order identical to scalar version.
// A row r -> A + (r/arpg)*agst + (r%arpg)*arst + aoff  (arpg in {1,3})
// BSEL: 0=B1 dense; 1=[Wa_src|Wa_dst|Wv0]; 2=[eW_src|eW_dst]
// ACT: 0 none; 2 swiglu across the 4 s-rows of each node
template<int K, int ACT, int BSEL>
__global__ __launch_bounds__(256) void k_gemm(const float* __restrict__ A,
        const float* __restrict__ B1, const float* __restrict__ B2,
        const float* __restrict__ bias, float* __restrict__ C,
        int M, int Nc, int ldc, int arpg, int agst, int arst, int aoff, int beta){
  constexpr int KP = (K+3)&~3;
  constexpr int SP = ((KP+4)%32==0) ? KP+8 : KP+4;   // 68/36/36 for K=64/32/26
  __shared__ alignas(16) float As[64*SP];
  __shared__ alignas(16) float Bs[KP*64];
  int tid = threadIdx.x, tm = blockIdx.x, tn = blockIdx.y;
  for (int i = tid; i < KP*64; i += 256){
    int kk = i >> 6, cl = i & 63;
    int c = tn*64 + cl;
    float v = 0.f;
    if (c < Nc && kk < K){
      if (BSEL == 0) v = B1[kk*Nc + c];
      else if (BSEL == 1) v = (c<8) ? B1[kk*8+c] : ((c<16) ? B1[(64+kk)*8 + (c-8)] : B2[kk*64 + (c-16)]);
      else v = (c<32) ? B1[kk*32 + c] : B1[(64+kk)*32 + (c-32)];
    }
    Bs[i] = v;
  }
  for (int i = tid; i < 64*KP; i += 256){
    int rl = i / KP, kk = i - rl*KP;
    int r = tm*64 + rl;
    float v = 0.f;
    if (r < M && kk < K){
      const float* ap;
      if (arpg == 1) ap = A + (size_t)r*agst + aoff;
      else { int g = r/3; int wr = r - g*3; ap = A + (size_t)g*agst + wr*arst + aoff; }
      v = ap[kk];
    }
    As[rl*SP + kk] = v;
  }
  __syncthreads();
  int tx = tid & 15, ty = tid >> 4;
  float acc[4][4] = {};
  #pragma unroll 2
  for (int kq = 0; kq < KP/4; ++kq){
    float4 a0 = *reinterpret_cast<const float4*>(&As[(ty*4+0)*SP + kq*4]);
    float4 a1 = *reinterpret_cast<const float4*>(&As[(ty*4+1)*SP + kq*4]);
    float4 a2 = *reinterpret_cast<const float4*>(&As[(ty*4+2)*SP + kq*4]);
    float4 a3 = *reinterpret_cast<const float4*>(&As[(ty*4+3)*SP + kq*4]);
    #pragma unroll
    for (int mm = 0; mm < 4; ++mm){
      float4 b4 = *reinterpret_cast<const float4*>(&Bs[(kq*4+mm)*64 + tx*4]);
      float e0 = (&a0.x)[mm], e1 = (&a1.x)[mm], e2 = (&a2.x)[mm], e3 = (&a3.x)[mm];
      acc[0][0] += e0*b4.x; acc[0][1] += e0*b4.y; acc[0][2] += e0*b4.z; acc[0][3] += e0*b4.w;
      acc[1][0] += e1*b4.x; acc[1][1] += e1*b4.y; acc[1][2] += e1*b4.z; acc[1][3] += e1*b4.w;
      acc[2][0] += e2*b4.x; acc[2][1] += e2*b4.y; acc[2][2] += e2*b4.z; acc[2][3] += e2*b4.w;
      acc[3][0] += e3*b4.x; acc[3][1] += e3*b4.y; acc[3][2] += e3*b4.z; acc[3][3] += e3*b4.w;
    }
  }
  if (ACT == 2){
    int r0 = tm*64 + ty*4;
    #pragma unroll
    for (int cc = 0; cc < 4; ++cc){
      int c = tn*64 + tx*4 + cc;
      if (c >= Nc) continue;
      float t0 = acc[0][cc];
      float g = 1.f/(1.f + expf(-t0));
      C[(size_t)(r0+0)*ldc + c] = t0*g;
      C[(size_t)(r0+1)*ldc + c] = acc[1][cc]*g;
      C[(size_t)(r0+2)*ldc + c] = acc[2][cc]*g;
      C[(size_t)(r0+3)*ldc + c] = acc[3][cc]*g;
    }
  } else {
    #pragma unroll
    for (int rr = 0; rr < 4; ++rr){
      int r = tm*64 + ty*4 + rr;
      if (r >= M) continue;
      #pragma unroll
      for (int cc = 0; cc < 4; ++cc){
        int c = tn*64 + tx*4 + cc;
        if (c >= Nc) continue;
        float v = acc[rr][cc];
        if (bias) v += bias[c];
        size_t ci = (size_t)r*ldc + c;
        if (beta) v += C[ci];
        C[ci] = v;
      }
    }
  }
}

// ---------------- fused attention ----------------
__global__ __launch_bounds__(256) void k_attn(const int* __restrict__ src,
        const float* __restrict__ NF, const float* __restrict__ V1,
        const float* __restrict__ ef, const float* __restrict__ WaE, float* __restrict__ o){
  int w = threadIdx.x >> 6, lane = threadIdx.x & 63;
  int n = blockIdx.x*4 + w;
  int h = lane >> 3, q = lane & 7;
  float w0 = WaE[(q*4+0)*8 + h];
  float w1 = WaE[(q*4+1)*8 + h];
  float w2 = WaE[(q*4+2)*8 + h];
  float w3 = WaE[(q*4+3)*8 + h];
  const int* sk = src + (size_t)n*KK;
  int myj = (lane < KK) ? sk[lane] : 0;
  float a2 = NF[(size_t)n*80 + 8 + h];
  float m = -INFINITY, s = 0.f, o0=0.f, o1=0.f, o2=0.f, o3=0.f;
  for (int k = 0; k < KK; ++k){
    int j = __shfl(myj, k);
    float4 e4 = *reinterpret_cast<const float4*>(ef + ((size_t)n*KK + k)*32 + q*4);
    float val = e4.x*w0 + e4.y*w1 + e4.z*w2 + e4.w*w3;
    val += __shfl_xor(val, 1);
    val += __shfl_xor(val, 2);
    val += __shfl_xor(val, 4);
    float l = val + NF[(size_t)j*80 + h] + a2;
    l = (l >= 0.f) ? l : 0.2f*l;
    float mn = fmaxf(m, l);
    float f = expf(m - mn);
    float pp = expf(l - mn);
    s = s*f + pp;
    const float* v1p = V1 + (size_t)j*192;
    o0 = o0*f + pp*NF[(size_t)j*80 + 16 + lane];
    o1 = o1*f + pp*v1p[lane];
    o2 = o2*f + pp*v1p[64+lane];
    o3 = o3*f + pp*v1p[128+lane];
    m = mn;
  }
  float inv = 1.f/s;
  float* op = o + (size_t)n*256;
  op[lane] = o0*inv; op[64+lane] = o1*inv; op[128+lane] = o2*inv; op[192+lane] = o3*inv;
}

// ---------------- fused so3: gate mini-GEMM + gather, one node per block ----------------
// C=32 (eb): single pass over 64 gate cols, 2k x 4c tiles, 256 active threads.
// C=91 (oa): two passes (92-col halves), 4k x 4c tiles, 184 active threads.
template<int C>
__global__ __launch_bounds__(256) void k_so3fused(const int* __restrict__ src,
        const float* __restrict__ ef, const float* __restrict__ Wrad,
        const float* __restrict__ brad, const float* __restrict__ Wgate,
        const float* __restrict__ M0, const float* __restrict__ M1,
        const float* __restrict__ lat, float* __restrict__ out, int nstr, int sstr){
  constexpr int KT = (C==32) ? 2 : 4;     // k per thread
  constexpr int KG = 32/KT;               // 16 / 8 k-groups
  constexpr int NQ = (C==32) ? 16 : 23;   // c-quads per pass
  constexpr int PW = (C==32) ? 32 : 92;   // part/padded width
  constexpr int CG = (C==32) ? 64 : 92;   // staged gate cols per pass
  constexpr int HS = 68;                  // Hs stride
  constexpr int NPASS = (C==32) ? 1 : 2;
  constexpr int NT = KG*NQ;               // 256 / 184
  constexpr int LD0 = PW;                 // M0 row stride
  constexpr int LD1 = PW;                 // M1 row stride (group = 3*LD1)
  __shared__ alignas(16) float uni[64*CG];   // efs+Wr, then Wg
  __shared__ alignas(16) float Hs[32*HS];
  __shared__ alignas(16) float part[4*KG*PW];
  __shared__ int js[32];
  float* efs = uni;            // [30*32]
  float* Wr  = uni + 30*32;    // [32*64]
  float* Wg  = uni;
  int n = blockIdx.x, tid = threadIdx.x;
  for (int i = tid; i < KK*32; i += 256) efs[i] = ef[(size_t)n*KK*32 + i];
  for (int i = tid; i < 2048;  i += 256) Wr[i]  = Wrad[i];
  if (tid < 32) js[tid] = (tid < KK) ? src[(size_t)n*KK + tid] : 0;
  __syncthreads();
  // H[k][h] = silu(ef_k @ Wrad + brad), rows 30,31 zero
  for (int i = tid; i < 32*64; i += 256){
    int k = i >> 6, h = i & 63;
    float v = 0.f;
    if (k < KK){
      float a = brad[h];
      const float* er = efs + k*32;
      #pragma unroll
      for (int m = 0; m < 32; ++m) a += er[m]*Wr[m*64 + h];
      v = a/(1.f + expf(-a));
    }
    Hs[k*HS + h] = v;
  }
  int kg = tid / NQ, cq = tid - kg*NQ;
  bool act = (tid < NT);
  for (int pass = 0; pass < NPASS; ++pass){
    __syncthreads();                      // H/prev-pass reads done
    for (int i = tid; i < 64*CG; i += 256){
      int m = i/CG, u = i - m*CG;
      float v = 0.f;
      if (C == 32) v = Wgate[m*64 + u];
      else if (u < 91) v = Wgate[m*182 + pass*91 + u];
      Wg[i] = v;
    }
    __syncthreads();
    if (act){
      float g[KT][4];
      #pragma unroll
      for (int i=0;i<KT;++i){ g[i][0]=0.f; g[i][1]=0.f; g[i][2]=0.f; g[i][3]=0.f; }
      #pragma unroll 2
      for (int mq = 0; mq < 16; ++mq){
        float4 hs[KT];
        #pragma unroll
        for (int i=0;i<KT;++i) hs[i] = *reinterpret_cast<const float4*>(&Hs[(kg*KT+i)*HS + mq*4]);
        #pragma unroll
        for (int mm=0; mm<4; ++mm){
          float4 w4 = *reinterpret_cast<const float4*>(&Wg[(mq*4+mm)*CG + cq*4]);
          #pragma unroll
          for (int i=0;i<KT;++i){
            float h = (&hs[i].x)[mm];
            g[i][0] += h*w4.x; g[i][1] += h*w4.y; g[i][2] += h*w4.z; g[i][3] += h*w4.w;
          }
        }
      }
      bool scalar_path = (C==32) ? (cq < 8) : (pass == 0);
      if (scalar_path){
        int c = cq*4;
        float a0x=0.f, a0y=0.f, a0z=0.f, a0w=0.f;
        #pragma unroll
        for (int i=0;i<KT;++i){
          int k = kg*KT+i;
          float4 m0 = *reinterpret_cast<const float4*>(&M0[(size_t)js[k]*LD0 + c]);
          a0x += g[i][0]*m0.x; a0y += g[i][1]*m0.y; a0z += g[i][2]*m0.z; a0w += g[i][3]*m0.w;
        }
        float4 r4; r4.x=a0x; r4.y=a0y; r4.z=a0z; r4.w=a0w;
        *reinterpret_cast<float4*>(&part[(0*KG+kg)*PW + c]) = r4;
      } else {
        int c = (C==32) ? (cq*4-32) : cq*4;
        float a1[4]={0,0,0,0}, a2[4]={0,0,0,0}, a3[4]={0,0,0,0};
        #pragma unroll
        for (int i=0;i<KT;++i){
          int k = kg*KT+i;
          const float* m1r = M1 + (size_t)js[k]*3*LD1;
          float4 v1 = *reinterpret_cast<const float4*>(&m1r[c]);
          float4 v2 = *reinterpret_cast<const float4*>(&m1r[LD1 + c]);
          float4 v3 = *reinterpret_cast<const float4*>(&m1r[2*LD1 + c]);
          a1[0]+=g[i][0]*v1.x; a1[1]+=g[i][1]*v1.y; a1[2]+=g[i][2]*v1.z; a1[3]+=g[i][3]*v1.w;
          a2[0]+=g[i][0]*v2.x; a2[1]+=g[i][1]*v2.y; a2[2]+=g[i][2]*v2.z; a2[3]+=g[i][3]*v2.w;
          a3[0]+=g[i][0]*v3.x; a3[1]+=g[i][1]*v3.y; a3[2]+=g[i][2]*v3.z; a3[3]+=g[i][3]*v3.w;
        }
        float4 r1; r1.x=a1[0]; r1.y=a1[1]; r1.z=a1[2]; r1.w=a1[3];
        float4 r2; r2.x=a2[0]; r2.y=a2[1]; r2.z=a2[2]; r2.w=a2[3];
        float4 r3; r3.x=a3[0]; r3.y=a3[1]; r3.z=a3[2]; r3.w=a3[3];
        *reinterpret_cast<float4*>(&part[(1*KG+kg)*PW + c]) = r1;
        *reinterpret_cast<float4*>(&part[(2*KG+kg)*PW + c]) = r2;
        *reinterpret_cast<float4*>(&part[(3*KG+kg)*PW + c]) = r3;
      }
    }
  }
  __syncthreads();
  const float IS = 0.18257418583505536f;  // 1/sqrt(30)
  for (int idx = tid; idx < 4*C; idx += 256){
    int r = idx / C, c = idx - r*C;
    float s = 0.f;
    #pragma unroll
    for (int gq = 0; gq < KG; ++gq) s += part[(r*KG+gq)*PW + c];
    out[(size_t)n*nstr + r*sstr + c] = s*IS;
  }
  if (C == 32){
    if (lat){
      for (int idx = tid; idx < 128; idx += 256){
        int r = idx >> 5, c = idx & 31;
        out[(size_t)n*nstr + r*sstr + 32 + c] = lat[(size_t)n*128 + r*32 + c];
      }
    }
  }
}

// ---------------- edge feature update (fused ef@eW_e matvec, in-place) ----------------
__global__ __launch_bounds__(256) void k_edgeout(const int* __restrict__ src,
        const float* __restrict__ eWe, const float* __restrict__ EE,
        const float* __restrict__ ebv, float* __restrict__ ef){
  __shared__ float ws[32*32];
  __shared__ float es[8*32];
  int tid = threadIdx.x;
  size_t e0 = (size_t)blockIdx.x*8;
  for (int i = tid; i < 1024; i += 256) ws[i] = eWe[i];
  es[tid] = ef[e0*32 + tid];
  __syncthreads();
  int le = tid >> 5, c = tid & 31;
  size_t e = e0 + le;
  int n = (int)(e / KK);
  int j = src[e];
  float acc = ebv[c] + EE[(size_t)j*64 + c] + EE[(size_t)n*64 + 32 + c];
  const float* er = es + le*32;
  #pragma unroll
  for (int kk = 0; kk < 32; ++kk) acc += er[kk]*ws[kk*32 + c];
  ef[e*32 + c] = tanhf(acc);
}

// ---------------- head ----------------
__global__ __launch_bounds__(128) void k_head(const float* __restrict__ atoms,
        const float* __restrict__ ln_g, const float* __restrict__ ln_b,
        const float* __restrict__ W_seq, const float* __restrict__ b_seq, float* __restrict__ out){
  __shared__ float red[128];
  __shared__ float nrm[91];
  __shared__ float lg[20];
  int n = blockIdx.x, t = threadIdx.x;
  const float* inv = atoms + (size_t)n*364;
  float x = (t < 91) ? inv[t] : 0.f;
  red[t] = x; __syncthreads();
  for (int off=64; off>=1; off>>=1){ if (t<off) red[t]+=red[t+off]; __syncthreads(); }
  float mu = red[0] / 91.f;
  __syncthreads();
  float d = x - mu;
  red[t] = (t<91) ? d*d : 0.f; __syncthreads();
  for (int off=64; off>=1; off>>=1){ if (t<off) red[t]+=red[t+off]; __syncthreads(); }
  float var = red[0] / 91.f;
  __syncthreads();
  if (t < 91) nrm[t] = (x - mu)/sqrtf(var + 1e-5f) * ln_g[t] + ln_b[t];
  __syncthreads();
  if (t < 20){
    float acc = b_seq[t];
    for (int c=0;c<91;++c) acc += nrm[c]*W_seq[c*20+t];
    lg[t] = acc;
  }
  __syncthreads();
  if (t == 0){
    float mx = lg[0];
    for (int i=1;i<20;++i) mx = fmaxf(mx, lg[i]);
    float s = 0.f;
    for (int i=0;i<20;++i) s += expf(lg[i]-mx);
    red[0] = mx + logf(s);
  }
  __syncthreads();
  float lse = red[0];
  if (t < 20) out[(size_t)NN*273 + (size_t)n*20 + t] = lg[t] - lse;
  for (int idx = t; idx < 273; idx += 128){
    int c = idx/3, i = idx - c*3;
    out[(size_t)n*273 + idx] = atoms[(size_t)n*364 + (1+i)*91 + c];
  }
}

// ---------------- host dispatch ----------------
static void gemm(hipStream_t st, int K, int act, int bsel, const float* A,
                 const float* B1, const float* B2, const float* bias, float* C,
                 int M, int Nc, int ldc, int arpg, int agst, int arst, int aoff, int beta){
  dim3 g((M+63)/64, (Nc+63)/64), b(256);
  if (K == 26){
    k_gemm<26,0,0><<<g,b,0,st>>>(A,B1,B2,bias,C,M,Nc,ldc,arpg,agst,arst,aoff,beta);
  } else if (K == 32){
    if (act == 2) k_gemm<32,2,0><<<g,b,0,st>>>(A,B1,B2,bias,C,M,Nc,ldc,arpg,agst,arst,aoff,beta);
    else          k_gemm<32,0,0><<<g,b,0,st>>>(A,B1,B2,bias,C,M,Nc,ldc,arpg,agst,arst,aoff,beta);
  } else {
    if (act == 2)        k_gemm<64,2,0><<<g,b,0,st>>>(A,B1,B2,bias,C,M,Nc,ldc,arpg,agst,arst,aoff,beta);
    else if (bsel == 1)  k_gemm<64,0,1><<<g,b,0,st>>>(A,B1,B2,bias,C,M,Nc,ldc,arpg,agst,arst,aoff,beta);
    else if (bsel == 2)  k_gemm<64,0,2><<<g,b,0,st>>>(A,B1,B2,bias,C,M,Nc,ldc,arpg,agst,arst,aoff,beta);
    else                 k_gemm<64,0,0><<<g,b,0,st>>>(A,B1,B2,bias,C,M,Nc,ldc,arpg,agst,arst,aoff,beta);
  }
}

extern "C" void kernel_launch(void* const* d_in, const int* in_sizes, int n_in,
                              void* d_out, int out_size, void* d_ws, size_t ws_size,
                              hipStream_t stream){
  (void)in_sizes; (void)n_in; (void)out_size;
  if (ws_size < WS_NEEDED) return;

  const float* bb      = (const float*)d_in[0];
  const float* latent  = (const float*)d_in[2];
  const float* eb_Wrad = (const float*)d_in[3];
  const float* eb_brad = (const float*)d_in[4];
  const float* eb_Wgate= (const float*)d_in[5];
  const float* eb_W0   = (const float*)d_in[6];
  const float* eb_W1   = (const float*)d_in[7];
  const float* t_Walpha= (const float*)d_in[8];
  const float* t_Wv0   = (const float*)d_in[9];
  const float* t_Wv1   = (const float*)d_in[10];
  const float* t_Wo    = (const float*)d_in[11];
  const float* t_Wf1   = (const float*)d_in[12];
  const float* t_Wf2   = (const float*)d_in[13];
  const float* e_W     = (const float*)d_in[14];
  const float* e_b     = (const float*)d_in[15];
  const float* p_Walpha= (const float*)d_in[16];
  const float* p_Wv0   = (const float*)d_in[17];
  const float* p_Wv1   = (const float*)d_in[18];
  const float* p_Wo    = (const float*)d_in[19];
  const float* p_Wf1   = (const float*)d_in[20];
  const float* p_Wf2   = (const float*)d_in[21];
  const float* oa_Wrad = (const float*)d_in[22];
  const float* oa_brad = (const float*)d_in[23];
  const float* oa_Wgate= (const float*)d_in[24];
  const float* oa_W0   = (const float*)d_in[25];
  const float* oa_W1   = (const float*)d_in[26];
  const float* ln_g    = (const float*)d_in[27];
  const float* ln_b    = (const float*)d_in[28];
  const float* W_seq   = (const float*)d_in[29];
  const float* b_seq   = (const float*)d_in[30];

  char* w = (char*)d_ws;
  int*   src = (int*)  (w + O_SRC);
  float* xs  = (float*)(w + O_XS);
  float* ys  = (float*)(w + O_YS);
  float* zs  = (float*)(w + O_ZS);
  float* bbe = (float*)(w + O_BBE);
  float* res = (float*)(w + O_RES);
  float* p   = (float*)(w + O_P);
  float* ef  = (float*)(w + O_EF);
  float* NF  = (float*)(w + O_NF);
  float* V1  = (float*)(w + O_V1);
  float* o   = (float*)(w + O_O);
  float* EE  = (float*)(w + O_EE);
  float* M0e = (float*)(w + O_M0E);
  float* M1e = (float*)(w + O_M1E);
  float* M0o = (float*)(w + O_M0O);
  float* M1o = (float*)(w + O_M1O);
  float* atm = (float*)(w + O_ATM);

  // ---- geometry ----
  k_prep <<<(NN+255)/256, 256, 0, stream>>>(bb, xs, ys, zs, bbe);
  k_dihed<<<(3*NN+255)/256, 256, 0, stream>>>(bb, bbe);
  k_knn  <<<NN/4, 256, 0, stream>>>(xs, ys, zs, src);
  k_edgefeat<<<(NE+255)/256, 256, 0, stream>>>(src, xs, ys, zs, ef);

  // ---- eb so3_conv -> res[:,:,0:32] (+latent -> cols 32:64) ----
  gemm(stream, 26,0,0, bbe, eb_W0, nullptr, nullptr, M0e, NN,   32, 32, 1,104, 0, 0, 0);
  gemm(stream, 26,0,0, bbe, eb_W1, nullptr, nullptr, M1e, 3*NN, 32, 32, 3,104,26,26, 0);
  k_so3fused<32><<<NN, 256, 0, stream>>>(src, ef, eb_Wrad, eb_brad, eb_Wgate, M0e, M1e, latent, res, 256, 64);

  // ---- transformer layers ----
  for (int L=0; L<4; ++L){
    const float* Wa  = t_Walpha + (size_t)L*160*8;
    const float* Wv0 = t_Wv0 + (size_t)L*64*64;
    const float* Wv1 = t_Wv1 + (size_t)L*64*64;
    const float* Wo  = t_Wo  + (size_t)L*64*64;
    const float* Wf1 = t_Wf1 + (size_t)L*64*64;
    const float* Wf2 = t_Wf2 + (size_t)L*64*64;
    const float* eWl = e_W   + (size_t)L*160*32;
    const float* ebl = e_b   + (size_t)L*32;
    gemm(stream, 64,0,1, res, Wa, Wv0, nullptr, NF, NN,   80, 80, 1,256, 0, 0, 0);
    gemm(stream, 64,0,0, res, Wv1, nullptr, nullptr, V1, 3*NN, 64, 64, 3,256,64,64, 0);
    k_attn<<<NN/4, 256, 0, stream>>>(src, NF, V1, ef, Wa + 128*8, o);
    gemm(stream, 64,0,0, o,   Wo,  nullptr, nullptr, res, 4*NN, 64, 64, 1,64,0,0, 1);
    gemm(stream, 64,2,0, res, Wf1, nullptr, nullptr, o,   4*NN, 64, 64, 1,64,0,0, 0);
    gemm(stream, 64,0,0, o,   Wf2, nullptr, nullptr, res, 4*NN, 64, 64, 1,64,0,0, 1);
    gemm(stream, 64,0,2, res, eWl, nullptr, nullptr, EE,  NN,   64, 64, 1,256,0,0, 0);
    k_edgeout<<<NE/8, 256, 0, stream>>>(src, eWl + 128*32, EE, ebl, ef);
  }

  // ---- p = attn(res) + ffn ----
  gemm(stream, 64,0,1, res, p_Walpha, p_Wv0, nullptr, NF, NN,   80, 80, 1,256, 0, 0, 0);
  gemm(stream, 64,0,0, res, p_Wv1, nullptr, nullptr, V1, 3*NN, 64, 64, 3,256,64,64, 0);
  k_attn<<<NN/4, 256, 0, stream>>>(src, NF, V1, ef, p_Walpha + 128*8, o);
  gemm(stream, 64,0,0, o, p_Wo,  nullptr, nullptr, p, 4*NN, 32, 32, 1,64,0,0, 0);
  gemm(stream, 32,2,0, p, p_Wf1, nullptr, nullptr, o, 4*NN, 32, 32, 1,32,0,0, 0);
  gemm(stream, 32,0,0, o, p_Wf2, nullptr, nullptr, p, 4*NN, 32, 32, 1,32,0,0, 1);

  // ---- oa so3_conv -> atoms (M0o/M1o ldc=92 for aligned gather) ----
  gemm(stream, 32,0,0, p, oa_W0, nullptr, nullptr, M0o, NN,   91, 92, 1,128, 0, 0, 0);
  gemm(stream, 32,0,0, p, oa_W1, nullptr, nullptr, M1o, 3*NN, 91, 92, 3,128,32,32, 0);
  k_so3fused<91><<<NN, 256, 0, stream>>>(src, ef, oa_Wrad, oa_brad, oa_Wgate, M0o, M1o, nullptr, atm, 364, 91);

  // ---- head ----
  k_head<<<NN, 128, 0, stream>>>(atm, ln_g, ln_b, W_seq, b_seq, (float*)d_out);
}

// Round 10
// 1296.182 us; speedup vs baseline: 3.4833x; 1.0575x over previous
//
#include <hip/hip_runtime.h>
#include <math.h>

// LatentDecoder on MI355X. All f32. Rotations R eliminated (orthogonal, cancel
// around per-channel gates). Per-edge linear maps commuted to per-node + gather.
// R1: KNN window-seeded threshold scan (exact).
// R2: alpha-edge logits fused into k_attn; ef@eW_e fused into k_edgeout.
// R3 (reverted): transposed-As GEMM -> VGPR 256 + LDS write conflicts.
// R4: fused gate MLP+gather (k_so3fused); swiglu in GEMM epilogue; no repack.
// R5: GEMM float4-across-kk core; so3fused register-tiled gate (measured R7:
//     so3fused<91> 262us, STALL-bound at 3 blocks/CU from 44.5KB LDS).
// R8: so3fused v2 — occupancy attack:
//     - Wgate read direct from global (L2-resident; repacked stride-184 for
//       C=91 so float4 reads align; zero pad cols). Deletes 23.5KB Wg LDS and
//       the 2-pass structure -> single pass, 230/256 lanes, barriers 6->3.
//     - Wrad LDS overlaid with part buffer (dead after H phase).
//     - LDS 44.5KB -> ~21KB -> 2x+ resident blocks/CU.
// R9/R10: identical to R8 (benches timed out on GPU acquisition — no data).

#define NN 8192
#define KK 30
#define NE (NN*KK)      // 245760
#define EPSF 1e-7f

// ---------------- workspace layout (bytes) ----------------
static const size_t O_SRC = 0;                  // int [NN*30]
static const size_t O_XS  = 1ull<<20;
static const size_t O_YS  = O_XS + (size_t)NN*4;
static const size_t O_ZS  = O_XS + (size_t)NN*8;
static const size_t O_BBE = 2ull<<20;           // float[NN*4*26]
static const size_t O_RES = 6ull<<20;           // float[NN*4*64]
static const size_t O_P   = 15ull<<20;          // float[NN*4*32]
static const size_t O_EF  = 20ull<<20;          // float[NE*32]    (ends 50MB)
// layer-phase scratch:
static const size_t O_NF  = 52ull<<20;          // float[NN*80]
static const size_t O_V1  = 55ull<<20;          // float[NN*3*64]
static const size_t O_O   = 62ull<<20;          // float[NN*4*64]
static const size_t O_EE  = 71ull<<20;          // float[NN*64]
// eb so3 phase (aliases layer scratch):
static const size_t O_M0E = 52ull<<20;          // float[NN*32]
static const size_t O_M1E = 54ull<<20;          // float[NN*3*32]
// oa so3 phase (aliases layer scratch + res/p, all dead by then):
static const size_t O_M0O = 52ull<<20;          // float[NN*92]    (ldc-padded)
static const size_t O_M1O = 56ull<<20;          // float[NN*3*92]  (ends 65MB)
static const size_t O_ATM = 6ull<<20;           // float[NN*4*91]
static const size_t O_WGO = 78ull<<20;          // float[64*184] repacked oa_Wgate
static const size_t WS_NEEDED = 80ull<<20;

// ---------------- small device helpers ----------------
__device__ __forceinline__ float nn0(float v){ return (v != v) ? 0.f : v; }
__device__ __forceinline__ void norm3(float& x, float& y, float& z){
  float s = sqrtf(x*x + y*y + z*z + EPSF);
  x /= s; y /= s; z /= s;
}

// ---------------- prep ----------------
__global__ void k_prep(const float* __restrict__ bb, float* __restrict__ xs,
                       float* __restrict__ ys, float* __restrict__ zs,
                       float* __restrict__ bbe){
  int n = blockIdx.x*blockDim.x + threadIdx.x;
  if (n >= NN) return;
  const float* bn = bb + (size_t)n*12;
  float a0x=bn[0],a0y=bn[1],a0z=bn[2];
  float cax=bn[3],cay=bn[4],caz=bn[5];
  float a2x=bn[6],a2y=bn[7],a2z=bn[8];
  float a3x=bn[9],a3y=bn[10],a3z=bn[11];
  xs[n]=cax; ys[n]=cay; zs[n]=caz;
  float v[7][3];
  v[0][0]=a0x-cax; v[0][1]=a0y-cay; v[0][2]=a0z-caz;
  v[1][0]=0.f;     v[1][1]=0.f;     v[1][2]=0.f;
  v[2][0]=a2x-cax; v[2][1]=a2y-cay; v[2][2]=a2z-caz;
  v[3][0]=a3x-cax; v[3][1]=a3y-cay; v[3][2]=a3z-caz;
  if (n < NN-1){
    float fx=bb[(size_t)(n+1)*12+3]-cax, fy=bb[(size_t)(n+1)*12+4]-cay, fz=bb[(size_t)(n+1)*12+5]-caz;
    norm3(fx,fy,fz); v[4][0]=fx; v[4][1]=fy; v[4][2]=fz;
  } else { v[4][0]=v[4][1]=v[4][2]=0.f; }
  if (n > 0){
    float gx=bb[(size_t)(n-1)*12+3]-cax, gy=bb[(size_t)(n-1)*12+4]-cay, gz=bb[(size_t)(n-1)*12+5]-caz;
    norm3(gx,gy,gz); v[5][0]=gx; v[5][1]=gy; v[5][2]=gz;
  } else { v[5][0]=v[5][1]=v[5][2]=0.f; }
  {
    float bx=cax-a0x, by=cay-a0y, bz=caz-a0z;
    float cx=a2x-cax, cy=a2y-cay, cz=a2z-caz;
    float ax = by*cz - bz*cy, ay = bz*cx - bx*cz, az = bx*cy - by*cx;
    v[6][0] = -0.58273431f*ax + 0.56802827f*bx - 0.54067466f*cx;
    v[6][1] = -0.58273431f*ay + 0.56802827f*by - 0.54067466f*cy;
    v[6][2] = -0.58273431f*az + 0.56802827f*bz - 0.54067466f*cz;
  }
  float* be = bbe + (size_t)n*104;
  #pragma unroll
  for (int c=6;c<26;++c) be[c]=0.f;
  #pragma unroll
  for (int s=0;s<3;++s){
    float* br = be + 26*(1+s);
    #pragma unroll
    for (int c=0;c<26;++c) br[c] = (c<7) ? nn0(v[c][s]) : 0.f;
  }
}

// ---------------- dihedrals ----------------
__global__ void k_dihed(const float* __restrict__ bb, float* __restrict__ bbe){
  int t = blockIdx.x*blockDim.x + threadIdx.x;
  if (t >= 3*NN) return;
  float cD = 1.f, sD = 0.f;
  if (t >= 1 && t < 3*NN-2){
    int i = t-1;
    float p[4][3];
    #pragma unroll
    for (int m=0;m<4;++m){
      int a = i+m; int rn = a/3, ra = a - rn*3;
      const float* q = bb + (size_t)(rn*4 + ra)*3;
      p[m][0]=q[0]; p[m][1]=q[1]; p[m][2]=q[2];
    }
    float u2x=p[1][0]-p[0][0], u2y=p[1][1]-p[0][1], u2z=p[1][2]-p[0][2];
    float u1x=p[2][0]-p[1][0], u1y=p[2][1]-p[1][1], u1z=p[2][2]-p[1][2];
    float u0x=p[3][0]-p[2][0], u0y=p[3][1]-p[2][1], u0z=p[3][2]-p[2][2];
    norm3(u2x,u2y,u2z); norm3(u1x,u1y,u1z); norm3(u0x,u0y,u0z);
    float n2x=u2y*u1z-u2z*u1y, n2y=u2z*u1x-u2x*u1z, n2z=u2x*u1y-u2y*u1x;
    float n1x=u1y*u0z-u1z*u0y, n1y=u1z*u0x-u1x*u0z, n1z=u1x*u0y-u1y*u0x;
    norm3(n2x,n2y,n2z); norm3(n1x,n1y,n1z);
    float cosD = n2x*n1x + n2y*n1y + n2z*n1z;
    const float lo = (float)(-1.0 + 1e-7), hi = (float)(1.0 - 1e-7);
    cosD = fminf(fmaxf(cosD, lo), hi);
    float sg = u2x*n1x + u2y*n1y + u2z*n1z;
    float sgn = (sg > 0.f) ? 1.f : ((sg < 0.f) ? -1.f : 0.f);
    float D = sgn * acosf(cosD);
    cD = cosf(D); sD = sinf(D);
  }
  int n = t/3, col = t - n*3;
  bbe[(size_t)n*104 + col] = cD;
  bbe[(size_t)n*104 + 3 + col] = sD;
}

// ---------------- KNN: wave per query, window-seeded exact top-30 ----------------
__global__ __launch_bounds__(256) void k_knn(const float* __restrict__ xs,
        const float* __restrict__ ys, const float* __restrict__ zs, int* __restrict__ src){
  __shared__ float sd[4][32];
  __shared__ int   si[4][32];
  int w = threadIdx.x >> 6, lane = threadIdx.x & 63;
  int n = blockIdx.x*4 + w;
  float qx = xs[n], qy = ys[n], qz = zs[n];
  if (lane >= 30 && lane < 32){ sd[w][lane] = INFINITY; si[w][lane] = 0; }

  int w0 = n - 32; if (w0 < 0) w0 = 0; if (w0 > NN-64) w0 = NN-64;
  int idx = w0 + lane;
  {
    float dx = qx - xs[idx], dy = qy - ys[idx], dz = qz - zs[idx];
    float d2 = dx*dx + dy*dy + dz*dz;
    if (idx == n) d2 = INFINITY;
    #pragma unroll
    for (int k = 2; k <= 64; k <<= 1){
      #pragma unroll
      for (int jj = k>>1; jj >= 1; jj >>= 1){
        float od = __shfl_xor(d2, jj);
        int   oi = __shfl_xor(idx, jj);
        bool up      = ((lane & k) == 0);
        bool lower   = ((lane & jj) == 0);
        bool takeMin = (up == lower);
        bool mless   = (d2 < od) || (d2 == od && idx < oi);
        if (mless != takeMin){ d2 = od; idx = oi; }
      }
    }
    if (lane < 30){ sd[w][lane] = d2; si[w][lane] = idx; }
  }
  float thr = sd[w][29];

  for (int s = 0; s < NN/64; ++s){
    int j = s*64 + lane;
    float dx = __fsub_rn(qx, xs[j]);
    float dy = __fsub_rn(qy, ys[j]);
    float dz = __fsub_rn(qz, zs[j]);
    float d2 = __fadd_rn(__fadd_rn(__fmul_rn(dx,dx),__fmul_rn(dy,dy)),__fmul_rn(dz,dz));
    if (j == n) d2 = INFINITY;
    if (j >= w0 && j < w0+64) d2 = INFINITY;
    unsigned long long bal = __ballot(d2 < thr);
    if (bal){
      while (bal){
        int b = __ffsll((unsigned long long)bal) - 1;
        bal &= bal - 1ull;
        float vd = __shfl(d2, b);
        int vj = s*64 + b;
        float dl = 0.f; int il = 0; bool keep = true;
        if (lane < 30){ dl = sd[w][lane]; il = si[w][lane]; keep = (dl <= vd); }
        unsigned long long km = __ballot(lane < 30 && keep);
        int pos = __popcll(km);
        if (lane < 30 && !keep){ sd[w][lane+1] = dl; si[w][lane+1] = il; }
        if (lane == pos){ sd[w][lane] = vd; si[w][lane] = vj; }
      }
      thr = sd[w][29];
    }
  }
  if (lane < 30) src[(size_t)n*KK + lane] = si[w][lane];
}

// ---------------- edge features: rbf(16) + pos_emb(16) ----------------
__global__ void k_edgefeat(const int* __restrict__ src, const float* __restrict__ xs,
        const float* __restrict__ ys, const float* __restrict__ zs, float* __restrict__ ef){
  int e = blockIdx.x*blockDim.x + threadIdx.x;
  if (e >= NE) return;
  int n = e / KK;
  int j = src[e];
  float vx = xs[j]-xs[n], vy = ys[j]-ys[n], vz = zs[j]-zs[n];
  float dist = sqrtf(vx*vx + vy*vy + vz*vz + EPSF);
  float* o = ef + (size_t)e*32;
  #pragma unroll
  for (int m=0;m<16;++m){
    float mu = (float)m * (20.f/15.f);
    float q = (dist - mu) / 1.25f;
    o[m] = expf(-q*q);
  }
  float d = (float)(j - n);
  const float Cf = -0.5756462732485115f;   // -ln(1e4)/16
  #pragma unroll
  for (int fi=0; fi<8; ++fi){
    float fr = expf((float)(2*fi) * Cf);
    float ang = d * fr;
    o[16+fi] = cosf(ang);
    o[24+fi] = sinf(ang);
  }
}

// ---------------- generic f32 GEMM: C[M,(ldc)Nc] = act(A@B) (+C if beta) ----
// Row-major As staged (conflict-free writes), float4 reads across kk for BOTH
// As and Bs: 8 b128 per 64 FMA. kk summation order identical to scalar version.
// A row r -> A + (r/arpg)*agst + (r%arpg)*arst + aoff  (arpg in {1,3})
// BSEL: 0=B1 dense; 1=[Wa_src|Wa_dst|Wv0]; 2=[eW_src|eW_dst]
// ACT: 0 none; 2 swiglu across the 4 s-rows of each node
template<int K, int ACT, int BSEL>
__global__ __launch_bounds__(256) void k_gemm(const float* __restrict__ A,
        const float* __restrict__ B1, const float* __restrict__ B2,
        const float* __restrict__ bias, float* __restrict__ C,
        int M, int Nc, int ldc, int arpg, int agst, int arst, int aoff, int beta){
  constexpr int KP = (K+3)&~3;
  constexpr int SP = ((KP+4)%32==0) ? KP+8 : KP+4;   // 68/36/36 for K=64/32/26
  __shared__ alignas(16) float As[64*SP];
  __shared__ alignas(16) float Bs[KP*64];
  int tid = threadIdx.x, tm = blockIdx.x, tn = blockIdx.y;
  for (int i = tid; i < KP*64; i += 256){
    int kk = i >> 6, cl = i & 63;
    int c = tn*64 + cl;
    float v = 0.f;
    if (c < Nc && kk < K){
      if (BSEL == 0) v = B1[kk*Nc + c];
      else if (BSEL == 1) v = (c<8) ? B1[kk*8+c] : ((c<16) ? B1[(64+kk)*8 + (c-8)] : B2[kk*64 + (c-16)]);
      else v = (c<32) ? B1[kk*32 + c] : B1[(64+kk)*32 + (c-32)];
    }
    Bs[i] = v;
  }
  for (int i = tid; i < 64*KP; i += 256){
    int rl = i / KP, kk = i - rl*KP;
    int r = tm*64 + rl;
    float v = 0.f;
    if (r < M && kk < K){
      const float* ap;
      if (arpg == 1) ap = A + (size_t)r*agst + aoff;
      else { int g = r/3; int wr = r - g*3; ap = A + (size_t)g*agst + wr*arst + aoff; }
      v = ap[kk];
    }
    As[rl*SP + kk] = v;
  }
  __syncthreads();
  int tx = tid & 15, ty = tid >> 4;
  float acc[4][4] = {};
  #pragma unroll 2
  for (int kq = 0; kq < KP/4; ++kq){
    float4 a0 = *reinterpret_cast<const float4*>(&As[(ty*4+0)*SP + kq*4]);
    float4 a1 = *reinterpret_cast<const float4*>(&As[(ty*4+1)*SP + kq*4]);
    float4 a2 = *reinterpret_cast<const float4*>(&As[(ty*4+2)*SP + kq*4]);
    float4 a3 = *reinterpret_cast<const float4*>(&As[(ty*4+3)*SP + kq*4]);
    #pragma unroll
    for (int mm = 0; mm < 4; ++mm){
      float4 b4 = *reinterpret_cast<const float4*>(&Bs[(kq*4+mm)*64 + tx*4]);
      float e0 = (&a0.x)[mm], e1 = (&a1.x)[mm], e2 = (&a2.x)[mm], e3 = (&a3.x)[mm];
      acc[0][0] += e0*b4.x; acc[0][1] += e0*b4.y; acc[0][2] += e0*b4.z; acc[0][3] += e0*b4.w;
      acc[1][0] += e1*b4.x; acc[1][1] += e1*b4.y; acc[1][2] += e1*b4.z; acc[1][3] += e1*b4.w;
      acc[2][0] += e2*b4.x; acc[2][1] += e2*b4.y; acc[2][2] += e2*b4.z; acc[2][3] += e2*b4.w;
      acc[3][0] += e3*b4.x; acc[3][1] += e3*b4.y; acc[3][2] += e3*b4.z; acc[3][3] += e3*b4.w;
    }
  }
  if (ACT == 2){
    int r0 = tm*64 + ty*4;
    #pragma unroll
    for (int cc = 0; cc < 4; ++cc){
      int c = tn*64 + tx*4 + cc;
      if (c >= Nc) continue;
      float t0 = acc[0][cc];
      float g = 1.f/(1.f + expf(-t0));
      C[(size_t)(r0+0)*ldc + c] = t0*g;
      C[(size_t)(r0+1)*ldc + c] = acc[1][cc]*g;
      C[(size_t)(r0+2)*ldc + c] = acc[2][cc]*g;
      C[(size_t)(r0+3)*ldc + c] = acc[3][cc]*g;
    }
  } else {
    #pragma unroll
    for (int rr = 0; rr < 4; ++rr){
      int r = tm*64 + ty*4 + rr;
      if (r >= M) continue;
      #pragma unroll
      for (int cc = 0; cc < 4; ++cc){
        int c = tn*64 + tx*4 + cc;
        if (c >= Nc) continue;
        float v = acc[rr][cc];
        if (bias) v += bias[c];
        size_t ci = (size_t)r*ldc + c;
        if (beta) v += C[ci];
        C[ci] = v;
      }
    }
  }
}

// ---------------- fused attention ----------------
__global__ __launch_bounds__(256) void k_attn(const int* __restrict__ src,
        const float* __restrict__ NF, const float* __restrict__ V1,
        const float* __restrict__ ef, const float* __restrict__ WaE, float* __restrict__ o){
  int w = threadIdx.x >> 6, lane = threadIdx.x & 63;
  int n = blockIdx.x*4 + w;
  int h = lane >> 3, q = lane & 7;
  float w0 = WaE[(q*4+0)*8 + h];
  float w1 = WaE[(q*4+1)*8 + h];
  float w2 = WaE[(q*4+2)*8 + h];
  float w3 = WaE[(q*4+3)*8 + h];
  const int* sk = src + (size_t)n*KK;
  int myj = (lane < KK) ? sk[lane] : 0;
  float a2 = NF[(size_t)n*80 + 8 + h];
  float m = -INFINITY, s = 0.f, o0=0.f, o1=0.f, o2=0.f, o3=0.f;
  for (int k = 0; k < KK; ++k){
    int j = __shfl(myj, k);
    float4 e4 = *reinterpret_cast<const float4*>(ef + ((size_t)n*KK + k)*32 + q*4);
    float val = e4.x*w0 + e4.y*w1 + e4.z*w2 + e4.w*w3;
    val += __shfl_xor(val, 1);
    val += __shfl_xor(val, 2);
    val += __shfl_xor(val, 4);
    float l = val + NF[(size_t)j*80 + h] + a2;
    l = (l >= 0.f) ? l : 0.2f*l;
    float mn = fmaxf(m, l);
    float f = expf(m - mn);
    float pp = expf(l - mn);
    s = s*f + pp;
    const float* v1p = V1 + (size_t)j*192;
    o0 = o0*f + pp*NF[(size_t)j*80 + 16 + lane];
    o1 = o1*f + pp*v1p[lane];
    o2 = o2*f + pp*v1p[64+lane];
    o3 = o3*f + pp*v1p[128+lane];
    m = mn;
  }
  float inv = 1.f/s;
  float* op = o + (size_t)n*256;
  op[lane] = o0*inv; op[64+lane] = o1*inv; op[128+lane] = o2*inv; op[192+lane] = o3*inv;
}

// ---------------- oa_Wgate repack: [64][182] -> [64][184], zero cols 91/183 ----
__global__ void k_wgrepack(const float* __restrict__ Wg, float* __restrict__ o){
  int i = blockIdx.x*blockDim.x + threadIdx.x;
  if (i >= 64*184) return;
  int m = i/184, c = i - m*184;
  float v = 0.f;
  if (c < 91) v = Wg[m*182 + c];
  else if (c >= 92 && c < 183) v = Wg[m*182 + 91 + (c - 92)];
  o[i] = v;
}

// ---------------- fused so3 v2: gate mini-GEMM (Wg from global) + gather ----
// One node per block. Single pass over all gate cols. LDS = efs + pool(Wr/part
// overlay) + Hs (~21KB -> high residency). C=32: 16 quads x 16 kg (all 256
// lanes). C=91: 46 quads x 5 kg (230 lanes), Wg pre-repacked to stride 184.
template<int C>
__global__ __launch_bounds__(256) void k_so3fused(const int* __restrict__ src,
        const float* __restrict__ ef, const float* __restrict__ Wrad,
        const float* __restrict__ brad, const float* __restrict__ Wg,
        const float* __restrict__ M0, const float* __restrict__ M1,
        const float* __restrict__ lat, float* __restrict__ out, int nstr, int sstr){
  constexpr int NQ   = (C==32) ? 16 : 46;   // col-quads (both halves)
  constexpr int KG   = (C==32) ? 16 : 5;    // k-groups
  constexpr int KT   = (C==32) ? 2  : 6;    // k per thread (KG*KT >= 30)
  constexpr int WGS  = (C==32) ? 64 : 184;  // Wg row stride (repacked for 91)
  constexpr int HALF = NQ/2;                // quads in scalar half
  constexpr int PW   = (C==32) ? 32 : 92;   // payload cols per half
  constexpr int PWS  = (PW%32==0) ? PW+4 : PW;  // part stride (bank spread)
  constexpr int LD0  = PW;                  // M0 row stride
  constexpr int LD1  = PW;                  // M1 s-row stride (node = 3*LD1)
  constexpr int POOL = (2048 > 4*KG*PWS) ? 2048 : 4*KG*PWS;
  __shared__ alignas(16) float efs[KK*32];  // 3840B
  __shared__ alignas(16) float pool[POOL];  // Wrad during H; part after
  __shared__ alignas(16) float Hs[32*68];   // 8704B
  __shared__ int js[32];
  int n = blockIdx.x, tid = threadIdx.x;
  for (int i = tid; i < KK*32; i += 256) efs[i] = ef[(size_t)n*KK*32 + i];
  for (int i = tid; i < 2048;  i += 256) pool[i] = Wrad[i];
  if (tid < 32) js[tid] = (tid < KK) ? src[(size_t)n*KK + tid] : 0;
  __syncthreads();
  // H[k][h] = silu(ef_k @ Wrad + brad); rows 30,31 zero
  for (int i = tid; i < 32*64; i += 256){
    int k = i >> 6, h = i & 63;
    float v = 0.f;
    if (k < KK){
      float a = brad[h];
      const float* er = efs + k*32;
      #pragma unroll
      for (int m = 0; m < 32; ++m) a += er[m]*pool[m*64 + h];
      v = a/(1.f + expf(-a));
    }
    Hs[k*68 + h] = v;
  }
  __syncthreads();                 // Wr dead beyond here; pool becomes part
  float* part = pool;
  int kg = tid / NQ, q = tid - kg*NQ;
  if (kg < KG){
    float g[KT][4];
    #pragma unroll
    for (int i=0;i<KT;++i){ g[i][0]=0.f; g[i][1]=0.f; g[i][2]=0.f; g[i][3]=0.f; }
    #pragma unroll 2
    for (int mq = 0; mq < 16; ++mq){
      float4 hs[KT];
      #pragma unroll
      for (int i=0;i<KT;++i) hs[i] = *reinterpret_cast<const float4*>(&Hs[(kg*KT+i)*68 + mq*4]);
      #pragma unroll
      for (int mm=0; mm<4; ++mm){
        float4 w4 = *reinterpret_cast<const float4*>(&Wg[(mq*4+mm)*WGS + q*4]);
        #pragma unroll
        for (int i=0;i<KT;++i){
          float h = (&hs[i].x)[mm];
          g[i][0] += h*w4.x; g[i][1] += h*w4.y; g[i][2] += h*w4.z; g[i][3] += h*w4.w;
        }
      }
    }
    if (q < HALF){
      int c = q*4;
      float a0[4] = {0.f,0.f,0.f,0.f};
      #pragma unroll
      for (int i=0;i<KT;++i){
        int k = kg*KT+i;
        float4 m0 = *reinterpret_cast<const float4*>(&M0[(size_t)js[k]*LD0 + c]);
        a0[0]+=g[i][0]*m0.x; a0[1]+=g[i][1]*m0.y; a0[2]+=g[i][2]*m0.z; a0[3]+=g[i][3]*m0.w;
      }
      float4 r0; r0.x=a0[0]; r0.y=a0[1]; r0.z=a0[2]; r0.w=a0[3];
      *reinterpret_cast<float4*>(&part[(0*KG+kg)*PWS + c]) = r0;
    } else {
      int c = (q-HALF)*4;
      float a1[4]={0.f,0.f,0.f,0.f}, a2[4]={0.f,0.f,0.f,0.f}, a3[4]={0.f,0.f,0.f,0.f};
      #pragma unroll
      for (int i=0;i<KT;++i){
        int k = kg*KT+i;
        const float* m1r = M1 + (size_t)js[k]*3*LD1;
        float4 v1 = *reinterpret_cast<const float4*>(&m1r[c]);
        float4 v2 = *reinterpret_cast<const float4*>(&m1r[LD1 + c]);
        float4 v3 = *reinterpret_cast<const float4*>(&m1r[2*LD1 + c]);
        a1[0]+=g[i][0]*v1.x; a1[1]+=g[i][1]*v1.y; a1[2]+=g[i][2]*v1.z; a1[3]+=g[i][3]*v1.w;
        a2[0]+=g[i][0]*v2.x; a2[1]+=g[i][1]*v2.y; a2[2]+=g[i][2]*v2.z; a2[3]+=g[i][3]*v2.w;
        a3[0]+=g[i][0]*v3.x; a3[1]+=g[i][1]*v3.y; a3[2]+=g[i][2]*v3.z; a3[3]+=g[i][3]*v3.w;
      }
      float4 r1; r1.x=a1[0]; r1.y=a1[1]; r1.z=a1[2]; r1.w=a1[3];
      float4 r2; r2.x=a2[0]; r2.y=a2[1]; r2.z=a2[2]; r2.w=a2[3];
      float4 r3; r3.x=a3[0]; r3.y=a3[1]; r3.z=a3[2]; r3.w=a3[3];
      *reinterpret_cast<float4*>(&part[(1*KG+kg)*PWS + c]) = r1;
      *reinterpret_cast<float4*>(&part[(2*KG+kg)*PWS + c]) = r2;
      *reinterpret_cast<float4*>(&part[(3*KG+kg)*PWS + c]) = r3;
    }
  }
  __syncthreads();
  const float IS = 0.18257418583505536f;  // 1/sqrt(30)
  for (int idx = tid; idx < 4*C; idx += 256){
    int r = idx / C, c = idx - r*C;
    float s = 0.f;
    #pragma unroll
    for (int gq = 0; gq < KG; ++gq) s += part[(r*KG+gq)*PWS + c];
    out[(size_t)n*nstr + r*sstr + c] = s*IS;
  }
  if (C == 32){
    if (lat){
      for (int idx = tid; idx < 128; idx += 256){
        int r = idx >> 5, c = idx & 31;
        out[(size_t)n*nstr + r*sstr + 32 + c] = lat[(size_t)n*128 + r*32 + c];
      }
    }
  }
}

// ---------------- edge feature update (fused ef@eW_e matvec, in-place) ----------------
__global__ __launch_bounds__(256) void k_edgeout(const int* __restrict__ src,
        const float* __restrict__ eWe, const float* __restrict__ EE,
        const float* __restrict__ ebv, float* __restrict__ ef){
  __shared__ float ws[32*32];
  __shared__ float es[8*32];
  int tid = threadIdx.x;
  size_t e0 = (size_t)blockIdx.x*8;
  for (int i = tid; i < 1024; i += 256) ws[i] = eWe[i];
  es[tid] = ef[e0*32 + tid];
  __syncthreads();
  int le = tid >> 5, c = tid & 31;
  size_t e = e0 + le;
  int n = (int)(e / KK);
  int j = src[e];
  float acc = ebv[c] + EE[(size_t)j*64 + c] + EE[(size_t)n*64 + 32 + c];
  const float* er = es + le*32;
  #pragma unroll
  for (int kk = 0; kk < 32; ++kk) acc += er[kk]*ws[kk*32 + c];
  ef[e*32 + c] = tanhf(acc);
}

// ---------------- head ----------------
__global__ __launch_bounds__(128) void k_head(const float* __restrict__ atoms,
        const float* __restrict__ ln_g, const float* __restrict__ ln_b,
        const float* __restrict__ W_seq, const float* __restrict__ b_seq, float* __restrict__ out){
  __shared__ float red[128];
  __shared__ float nrm[91];
  __shared__ float lg[20];
  int n = blockIdx.x, t = threadIdx.x;
  const float* inv = atoms + (size_t)n*364;
  float x = (t < 91) ? inv[t] : 0.f;
  red[t] = x; __syncthreads();
  for (int off=64; off>=1; off>>=1){ if (t<off) red[t]+=red[t+off]; __syncthreads(); }
  float mu = red[0] / 91.f;
  __syncthreads();
  float d = x - mu;
  red[t] = (t<91) ? d*d : 0.f; __syncthreads();
  for (int off=64; off>=1; off>>=1){ if (t<off) red[t]+=red[t+off]; __syncthreads(); }
  float var = red[0] / 91.f;
  __syncthreads();
  if (t < 91) nrm[t] = (x - mu)/sqrtf(var + 1e-5f) * ln_g[t] + ln_b[t];
  __syncthreads();
  if (t < 20){
    float acc = b_seq[t];
    for (int c=0;c<91;++c) acc += nrm[c]*W_seq[c*20+t];
    lg[t] = acc;
  }
  __syncthreads();
  if (t == 0){
    float mx = lg[0];
    for (int i=1;i<20;++i) mx = fmaxf(mx, lg[i]);
    float s = 0.f;
    for (int i=0;i<20;++i) s += expf(lg[i]-mx);
    red[0] = mx + logf(s);
  }
  __syncthreads();
  float lse = red[0];
  if (t < 20) out[(size_t)NN*273 + (size_t)n*20 + t] = lg[t] - lse;
  for (int idx = t; idx < 273; idx += 128){
    int c = idx/3, i = idx - c*3;
    out[(size_t)n*273 + idx] = atoms[(size_t)n*364 + (1+i)*91 + c];
  }
}

// ---------------- host dispatch ----------------
static void gemm(hipStream_t st, int K, int act, int bsel, const float* A,
                 const float* B1, const float* B2, const float* bias, float* C,
                 int M, int Nc, int ldc, int arpg, int agst, int arst, int aoff, int beta){
  dim3 g((M+63)/64, (Nc+63)/64), b(256);
  if (K == 26){
    k_gemm<26,0,0><<<g,b,0,st>>>(A,B1,B2,bias,C,M,Nc,ldc,arpg,agst,arst,aoff,beta);
  } else if (K == 32){
    if (act == 2) k_gemm<32,2,0><<<g,b,0,st>>>(A,B1,B2,bias,C,M,Nc,ldc,arpg,agst,arst,aoff,beta);
    else          k_gemm<32,0,0><<<g,b,0,st>>>(A,B1,B2,bias,C,M,Nc,ldc,arpg,agst,arst,aoff,beta);
  } else {
    if (act == 2)        k_gemm<64,2,0><<<g,b,0,st>>>(A,B1,B2,bias,C,M,Nc,ldc,arpg,agst,arst,aoff,beta);
    else if (bsel == 1)  k_gemm<64,0,1><<<g,b,0,st>>>(A,B1,B2,bias,C,M,Nc,ldc,arpg,agst,arst,aoff,beta);
    else if (bsel == 2)  k_gemm<64,0,2><<<g,b,0,st>>>(A,B1,B2,bias,C,M,Nc,ldc,arpg,agst,arst,aoff,beta);
    else                 k_gemm<64,0,0><<<g,b,0,st>>>(A,B1,B2,bias,C,M,Nc,ldc,arpg,agst,arst,aoff,beta);
  }
}

extern "C" void kernel_launch(void* const* d_in, const int* in_sizes, int n_in,
                              void* d_out, int out_size, void* d_ws, size_t ws_size,
                              hipStream_t stream){
  (void)in_sizes; (void)n_in; (void)out_size;
  if (ws_size < WS_NEEDED) return;

  const float* bb      = (const float*)d_in[0];
  const float* latent  = (const float*)d_in[2];
  const float* eb_Wrad = (const float*)d_in[3];
  const float* eb_brad = (const float*)d_in[4];
  const float* eb_Wgate= (const float*)d_in[5];
  const float* eb_W0   = (const float*)d_in[6];
  const float* eb_W1   = (const float*)d_in[7];
  const float* t_Walpha= (const float*)d_in[8];
  const float* t_Wv0   = (const float*)d_in[9];
  const float* t_Wv1   = (const float*)d_in[10];
  const float* t_Wo    = (const float*)d_in[11];
  const float* t_Wf1   = (const float*)d_in[12];
  const float* t_Wf2   = (const float*)d_in[13];
  const float* e_W     = (const float*)d_in[14];
  const float* e_b     = (const float*)d_in[15];
  const float* p_Walpha= (const float*)d_in[16];
  const float* p_Wv0   = (const float*)d_in[17];
  const float* p_Wv1   = (const float*)d_in[18];
  const float* p_Wo    = (const float*)d_in[19];
  const float* p_Wf1   = (const float*)d_in[20];
  const float* p_Wf2   = (const float*)d_in[21];
  const float* oa_Wrad = (const float*)d_in[22];
  const float* oa_brad = (const float*)d_in[23];
  const float* oa_Wgate= (const float*)d_in[24];
  const float* oa_W0   = (const float*)d_in[25];
  const float* oa_W1   = (const float*)d_in[26];
  const float* ln_g    = (const float*)d_in[27];
  const float* ln_b    = (const float*)d_in[28];
  const float* W_seq   = (const float*)d_in[29];
  const float* b_seq   = (const float*)d_in[30];

  char* w = (char*)d_ws;
  int*   src = (int*)  (w + O_SRC);
  float* xs  = (float*)(w + O_XS);
  float* ys  = (float*)(w + O_YS);
  float* zs  = (float*)(w + O_ZS);
  float* bbe = (float*)(w + O_BBE);
  float* res = (float*)(w + O_RES);
  float* p   = (float*)(w + O_P);
  float* ef  = (float*)(w + O_EF);
  float* NF  = (float*)(w + O_NF);
  float* V1  = (float*)(w + O_V1);
  float* o   = (float*)(w + O_O);
  float* EE  = (float*)(w + O_EE);
  float* M0e = (float*)(w + O_M0E);
  float* M1e = (float*)(w + O_M1E);
  float* M0o = (float*)(w + O_M0O);
  float* M1o = (float*)(w + O_M1O);
  float* atm = (float*)(w + O_ATM);
  float* Wgo = (float*)(w + O_WGO);

  // ---- geometry ----
  k_prep <<<(NN+255)/256, 256, 0, stream>>>(bb, xs, ys, zs, bbe);
  k_dihed<<<(3*NN+255)/256, 256, 0, stream>>>(bb, bbe);
  k_knn  <<<NN/4, 256, 0, stream>>>(xs, ys, zs, src);
  k_edgefeat<<<(NE+255)/256, 256, 0, stream>>>(src, xs, ys, zs, ef);

  // ---- eb so3_conv -> res[:,:,0:32] (+latent -> cols 32:64) ----
  gemm(stream, 26,0,0, bbe, eb_W0, nullptr, nullptr, M0e, NN,   32, 32, 1,104, 0, 0, 0);
  gemm(stream, 26,0,0, bbe, eb_W1, nullptr, nullptr, M1e, 3*NN, 32, 32, 3,104,26,26, 0);
  k_so3fused<32><<<NN, 256, 0, stream>>>(src, ef, eb_Wrad, eb_brad, eb_Wgate, M0e, M1e, latent, res, 256, 64);

  // ---- transformer layers ----
  for (int L=0; L<4; ++L){
    const float* Wa  = t_Walpha + (size_t)L*160*8;
    const float* Wv0 = t_Wv0 + (size_t)L*64*64;
    const float* Wv1 = t_Wv1 + (size_t)L*64*64;
    const float* Wo  = t_Wo  + (size_t)L*64*64;
    const float* Wf1 = t_Wf1 + (size_t)L*64*64;
    const float* Wf2 = t_Wf2 + (size_t)L*64*64;
    const float* eWl = e_W   + (size_t)L*160*32;
    const float* ebl = e_b   + (size_t)L*32;
    gemm(stream, 64,0,1, res, Wa, Wv0, nullptr, NF, NN,   80, 80, 1,256, 0, 0, 0);
    gemm(stream, 64,0,0, res, Wv1, nullptr, nullptr, V1, 3*NN, 64, 64, 3,256,64,64, 0);
    k_attn<<<NN/4, 256, 0, stream>>>(src, NF, V1, ef, Wa + 128*8, o);
    gemm(stream, 64,0,0, o,   Wo,  nullptr, nullptr, res, 4*NN, 64, 64, 1,64,0,0, 1);
    gemm(stream, 64,2,0, res, Wf1, nullptr, nullptr, o,   4*NN, 64, 64, 1,64,0,0, 0);
    gemm(stream, 64,0,0, o,   Wf2, nullptr, nullptr, res, 4*NN, 64, 64, 1,64,0,0, 1);
    gemm(stream, 64,0,2, res, eWl, nullptr, nullptr, EE,  NN,   64, 64, 1,256,0,0, 0);
    k_edgeout<<<NE/8, 256, 0, stream>>>(src, eWl + 128*32, EE, ebl, ef);
  }

  // ---- p = attn(res) + ffn ----
  gemm(stream, 64,0,1, res, p_Walpha, p_Wv0, nullptr, NF, NN,   80, 80, 1,256, 0, 0, 0);
  gemm(stream, 64,0,0, res, p_Wv1, nullptr, nullptr, V1, 3*NN, 64, 64, 3,256,64,64, 0);
  k_attn<<<NN/4, 256, 0, stream>>>(src, NF, V1, ef, p_Walpha + 128*8, o);
  gemm(stream, 64,0,0, o, p_Wo,  nullptr, nullptr, p, 4*NN, 32, 32, 1,64,0,0, 0);
  gemm(stream, 32,2,0, p, p_Wf1, nullptr, nullptr, o, 4*NN, 32, 32, 1,32,0,0, 0);
  gemm(stream, 32,0,0, o, p_Wf2, nullptr, nullptr, p, 4*NN, 32, 32, 1,32,0,0, 1);

  // ---- oa so3_conv -> atoms (M0o/M1o ldc=92; Wgate repacked stride 184) ----
  gemm(stream, 32,0,0, p, oa_W0, nullptr, nullptr, M0o, NN,   91, 92, 1,128, 0, 0, 0);
  gemm(stream, 32,0,0, p, oa_W1, nullptr, nullptr, M1o, 3*NN, 91, 92, 3,128,32,32, 0);
  k_wgrepack<<<46, 256, 0, stream>>>(oa_Wgate, Wgo);
  k_so3fused<91><<<NN, 256, 0, stream>>>(src, ef, oa_Wrad, oa_brad, Wgo, M0o, M1o, nullptr, atm, 364, 91);

  // ---- head ----
  k_head<<<NN, 128, 0, stream>>>(atm, ln_g, ln_b, W_seq, b_seq, (float*)d_out);
}